// Round 15
// baseline (973.626 us; speedup 1.0000x reference)
//
#include <hip/hip_runtime.h>
#include <hip/hip_bf16.h>

#define Tn 8192
#define Dn 1024
#define Fn 4096
#define SHn 2048
#define En 16
#define CAPn 1024

typedef __bf16 bf16_t;
typedef bf16_t bf16x8 __attribute__((ext_vector_type(8)));
typedef float f32x4 __attribute__((ext_vector_type(4)));

__device__ __forceinline__ unsigned short f2bf(float f) {
  unsigned int u = __builtin_bit_cast(unsigned int, f);
  u += 0x7FFFu + ((u >> 16) & 1u);
  return (unsigned short)(u >> 16);
}
__device__ __forceinline__ unsigned int pack2(float a, float b) {
  return (unsigned int)f2bf(a) | ((unsigned int)f2bf(b) << 16);
}

__device__ __forceinline__ void gload16(const void* g, void* l) {
  __builtin_amdgcn_global_load_lds(
      (const __attribute__((address_space(1))) unsigned int*)g,
      (__attribute__((address_space(3))) unsigned int*)l, 16, 0, 0);
}

// simple grid-stride fp32->bf16 over up to two tensors
__device__ __forceinline__ void conv_blocks(int cb, int ncb, int tid,
                                            const float* s1, unsigned short* d1, int n1,
                                            const float* s2, unsigned short* d2, int n2) {
  const int tot = n1 + n2;
  for (int i = cb * 256 + tid; i < tot; i += ncb * 256) {
    const float4* sv; uint4* dv; int j;
    if (i < n1) { j = i; sv = (const float4*)s1; dv = (uint4*)d1; }
    else        { j = i - n1; sv = (const float4*)s2; dv = (uint4*)d2; }
    float4 a = sv[2 * j], b = sv[2 * j + 1];
    dv[j] = uint4{ pack2(a.x, a.y), pack2(a.z, a.w), pack2(b.x, b.y), pack2(b.z, b.w) };
  }
}

// 4-way-ILP grid-stride fp32->bf16 (single tensor)
__device__ __forceinline__ void conv4(int cb, int ncb, int tid,
                                      const float* __restrict__ s,
                                      unsigned short* __restrict__ d, int n8) {
  const int step = ncb * 256;
  const float4* sv = (const float4*)s;
  uint4* dv = (uint4*)d;
  for (int i = cb * 256 + tid; i < n8; i += 4 * step) {
    const int i1 = i + step, i2 = i + 2 * step, i3 = i + 3 * step;
    const bool v1 = i1 < n8, v2 = i2 < n8, v3 = i3 < n8;
    float4 a0 = sv[2 * i], b0 = sv[2 * i + 1];
    float4 a1{}, b1{}, a2{}, b2{}, a3{}, b3{};
    if (v1) { a1 = sv[2 * i1]; b1 = sv[2 * i1 + 1]; }
    if (v2) { a2 = sv[2 * i2]; b2 = sv[2 * i2 + 1]; }
    if (v3) { a3 = sv[2 * i3]; b3 = sv[2 * i3 + 1]; }
    dv[i] = uint4{ pack2(a0.x, a0.y), pack2(a0.z, a0.w), pack2(b0.x, b0.y), pack2(b0.z, b0.w) };
    if (v1) dv[i1] = uint4{ pack2(a1.x, a1.y), pack2(a1.z, a1.w), pack2(b1.x, b1.y), pack2(b1.z, b1.w) };
    if (v2) dv[i2] = uint4{ pack2(a2.x, a2.y), pack2(a2.z, a2.w), pack2(b2.x, b2.y), pack2(b2.z, b2.w) };
    if (v3) dv[i3] = uint4{ pack2(a3.x, a3.y), pack2(a3.z, a3.w), pack2(b3.x, b3.y), pack2(b3.z, b3.w) };
  }
}

// ---------------- K1: gate scores + x->bf16 + ALL weight converts (standalone-speed) ----------------
// blocks [0,Tn): one token each. [Tn, Tn+2048): grid-stride convert of up_w, gw, down_w, shared.
__global__ __launch_bounds__(256) void kscores_cvt(
    const float* __restrict__ x, const float* __restrict__ gatew,
    float* __restrict__ sc, unsigned short* __restrict__ xb,
    const float* __restrict__ upw, unsigned short* __restrict__ upb,
    const float* __restrict__ gw, unsigned short* __restrict__ gwb,
    const float* __restrict__ dw, unsigned short* __restrict__ dwb,
    const float* __restrict__ shg, unsigned short* __restrict__ shgb,
    const float* __restrict__ shu, unsigned short* __restrict__ shub,
    const float* __restrict__ shd, unsigned short* __restrict__ shdb) {
  __shared__ float sx[Dn];
  const int tid = threadIdx.x;
  if (blockIdx.x >= Tn) {
    const int cb = blockIdx.x - Tn, ncb = gridDim.x - Tn;
    constexpr int NWE8 = En * Fn * Dn / 8;
    constexpr int nsh = SHn * Dn / 8;
    conv4(cb, ncb, tid, upw, upb, NWE8);
    conv4(cb, ncb, tid, gw, gwb, NWE8);
    conv4(cb, ncb, tid, dw, dwb, NWE8);
    conv_blocks(cb, ncb, tid, shg, shgb, nsh, shu, shub, nsh);
    conv_blocks(cb, ncb, tid, shd, shdb, nsh, nullptr, nullptr, 0);
    return;
  }
  const int tok = blockIdx.x;
  float4 v = ((const float4*)(x + (size_t)tok * Dn))[tid];
  ((float4*)sx)[tid] = v;
  ((uint2*)(xb + (size_t)tok * Dn))[tid] = uint2{ pack2(v.x, v.y), pack2(v.z, v.w) };
  __syncthreads();
  int e = tid >> 4, kl = tid & 15;
  const float4* w = (const float4*)(gatew + e * Dn);
  const float4* xv = (const float4*)sx;
  float acc = 0.f;
#pragma unroll
  for (int j = 0; j < 16; ++j) {
    float4 a = w[kl + 16 * j], b = xv[kl + 16 * j];
    acc += a.x * b.x + a.y * b.y + a.z * b.z + a.w * b.w;
  }
#pragma unroll
  for (int off = 8; off; off >>= 1) acc += __shfl_xor(acc, off, 64);
  if (kl == 0) sc[(size_t)e * Tn + tok] = 1.f / (1.f + expf(-acc));
}

// ---------------- per-expert top-CAP radix select (ties: lowest index) ----------------
__global__ __launch_bounds__(256) void kselect(const float* __restrict__ scores,
                                               int* __restrict__ ids,
                                               float* __restrict__ oscore) {
  __shared__ unsigned int keys[Tn];
  __shared__ unsigned int hist[256];
  __shared__ unsigned int sh_prefix, sh_k, sh_cnt, sh_eq;
  __shared__ int eqlist[1024];
  const int tid = threadIdx.x, e = blockIdx.x;
  const float* row = scores + (size_t)e * Tn;
  for (int i = 0; i < Tn / 256; ++i)
    keys[tid + i * 256] = __float_as_uint(row[tid + i * 256]);
  if (tid == 0) { sh_prefix = 0u; sh_k = CAPn; }
  __syncthreads();
  for (int shift = 24; shift >= 0; shift -= 8) {
    hist[tid] = 0u;
    __syncthreads();
    unsigned int prefix = sh_prefix;
    unsigned int mask = (shift == 24) ? 0u : (0xFFFFFFFFu << (shift + 8));
    for (int i = 0; i < Tn / 256; ++i) {
      unsigned int kk = keys[tid + i * 256];
      if ((kk & mask) == prefix) atomicAdd(&hist[(kk >> shift) & 255], 1u);
    }
    __syncthreads();
    if (tid == 0) {
      unsigned int k = sh_k, c = 0; int b;
      for (b = 255; b >= 0; --b) { c += hist[b]; if (c >= k) break; }
      sh_k = k - (c - hist[b]);
      sh_prefix = prefix | ((unsigned int)b << shift);
    }
    __syncthreads();
  }
  const unsigned int thr = sh_prefix;
  if (tid == 0) { sh_cnt = 0u; sh_eq = 0u; }
  __syncthreads();
  const int base = e * CAPn;
  for (int i = 0; i < Tn / 256; ++i) {
    int t = tid + i * 256;
    unsigned int kk = keys[t];
    if (kk > thr) {
      unsigned int p = atomicAdd(&sh_cnt, 1u);
      ids[base + p] = t;
      oscore[base + p] = __uint_as_float(kk);
    } else if (kk == thr) {
      unsigned int p = atomicAdd(&sh_eq, 1u);
      if (p < 1024u) eqlist[p] = t;
    }
  }
  __syncthreads();
  if (tid == 0) {
    int need = CAPn - (int)sh_cnt;
    int m = (int)sh_eq; if (m > 1024) m = 1024;
    for (int j = 0; j < need; ++j) {
      int best = 1 << 30, bi = 0;
      for (int i2 = 0; i2 < m; ++i2)
        if (eqlist[i2] < best) { best = eqlist[i2]; bi = i2; }
      eqlist[bi] = 1 << 30;
      ids[base + (int)sh_cnt + j] = best;
      oscore[base + (int)sh_cnt + j] = __uint_as_float(thr);
    }
  }
}

// =====================================================================
// Clean round-2 GEMMs (2-phase, 128x128, 16x16x32 MFMA, (256,2),
// global_load_lds + both-sides XOR swizzle, bm-fastest + XCD chunk
// swizzle). No fused conv anywhere.
// =====================================================================

// GLU: H = bf16( silu(A@Wg^T + bg) * (A@Wu^T + bu) ), K = Dn
template <bool GATHER>
__global__ __launch_bounds__(256, 2) void kglu_bf(
    const unsigned short* __restrict__ X, const int* __restrict__ idsg,
    const unsigned short* __restrict__ Wg, const unsigned short* __restrict__ Wu,
    const float* __restrict__ biasg, const float* __restrict__ biasu,
    unsigned short* __restrict__ H, int N, int Mz, int MB, int NB) {
  constexpr int K = Dn;
  __shared__ alignas(16) unsigned char sA[16384];
  __shared__ alignas(16) unsigned char sB1[16384];
  __shared__ alignas(16) unsigned char sB2[16384];
  __shared__ int sIds[128];
  const int tid = threadIdx.x;
  const int bid = blockIdx.x;
  const int cpx = gridDim.x >> 3;
  const int swz = (bid & 7) * cpx + (bid >> 3);
  const int bm = swz % MB;
  const int bn = (swz / MB) % NB;
  const int z  = swz / (MB * NB);
  const int lane = tid & 63, w = tid >> 6;
  const int wm = w >> 1, wn = w & 1;
  const int lrow = lane & 15, lk = lane >> 4;
  const int row0 = bm * 128;

  if (tid < 128) sIds[tid] = GATHER ? idsg[z * CAPn + row0 + tid] : (row0 + tid);
  __syncthreads();

  const int lr = lane >> 3;
  const int lc = lane & 7;
  const int srcb = ((lc ^ lr) << 4);
  const unsigned char* Xb = (const unsigned char*)X;
  const unsigned char* Gb = (const unsigned char*)Wg + (size_t)z * N * (K * 2);
  const unsigned char* Ub = (const unsigned char*)Wu + (size_t)z * N * (K * 2);
  const unsigned char* aP[4];
#pragma unroll
  for (int i = 0; i < 4; ++i) {
    int ar = w * 32 + 8 * i + lr;
    aP[i] = Xb + (size_t)sIds[ar] * (K * 2) + srcb;
  }
  const int br0 = bn * 128 + w * 32 + lr;
  const unsigned char* gP0 = Gb + (size_t)br0 * (K * 2) + srcb;
  const unsigned char* uP0 = Ub + (size_t)br0 * (K * 2) + srcb;

  f32x4 accG[4][4], accU[4][4];
#pragma unroll
  for (int m = 0; m < 4; ++m)
#pragma unroll
    for (int n = 0; n < 4; ++n) {
      accG[m][n] = {0.f, 0.f, 0.f, 0.f};
      accU[m][n] = {0.f, 0.f, 0.f, 0.f};
    }

  for (int k0b = 0; k0b < K * 2; k0b += 128) {
    __syncthreads();
#pragma unroll
    for (int i = 0; i < 4; ++i) {
      unsigned ldsoff = (unsigned)(w * 32 + 8 * i) * 128u;
      gload16(aP[i] + k0b, sA + ldsoff);
      gload16(gP0 + (size_t)i * 8 * (K * 2) + k0b, sB1 + ldsoff);
      gload16(uP0 + (size_t)i * 8 * (K * 2) + k0b, sB2 + ldsoff);
    }
    __syncthreads();
#pragma unroll
    for (int ks = 0; ks < 2; ++ks) {
      const int swb = (((ks * 4 + lk) ^ (lrow & 7)) << 4);
      bf16x8 av[4], gv[4], uv[4];
#pragma unroll
      for (int m = 0; m < 4; ++m)
        av[m] = *(const bf16x8*)(sA + (wm * 64 + m * 16 + lrow) * 128 + swb);
#pragma unroll
      for (int n = 0; n < 4; ++n) {
        gv[n] = *(const bf16x8*)(sB1 + (wn * 64 + n * 16 + lrow) * 128 + swb);
        uv[n] = *(const bf16x8*)(sB2 + (wn * 64 + n * 16 + lrow) * 128 + swb);
      }
#pragma unroll
      for (int m = 0; m < 4; ++m)
#pragma unroll
        for (int n = 0; n < 4; ++n) {
          accG[m][n] = __builtin_amdgcn_mfma_f32_16x16x32_bf16(av[m], gv[n], accG[m][n], 0, 0, 0);
          accU[m][n] = __builtin_amdgcn_mfma_f32_16x16x32_bf16(av[m], uv[n], accU[m][n], 0, 0, 0);
        }
    }
  }
#pragma unroll
  for (int n = 0; n < 4; ++n) {
    int col = bn * 128 + wn * 64 + n * 16 + lrow;
    float bg = biasg ? biasg[(size_t)z * N + col] : 0.f;
    float bu = biasu ? biasu[(size_t)z * N + col] : 0.f;
#pragma unroll
    for (int m = 0; m < 4; ++m) {
#pragma unroll
      for (int j = 0; j < 4; ++j) {
        float g = accG[m][n][j] + bg;
        float u = accU[m][n][j] + bu;
        float h = g / (1.f + __expf(-g)) * u;
        int row = row0 + wm * 64 + m * 16 + lk * 4 + j;
        H[(size_t)z * Mz * N + (size_t)row * N + col] = f2bf(h);
      }
    }
  }
}

// shared down: Out = A@W^T dense store, BM=128 BN=128, K = SHn
template <int K>
__global__ __launch_bounds__(256, 2) void kdown_bf(
    const unsigned short* __restrict__ Hin, const unsigned short* __restrict__ W,
    float* __restrict__ Out, int Mz, int MB, int NB) {
  constexpr int N = Dn;
  __shared__ alignas(16) unsigned char sA[16384];
  __shared__ alignas(16) unsigned char sB[16384];
  const int tid = threadIdx.x;
  const int bid = blockIdx.x;
  const int cpx = gridDim.x >> 3;
  const int swz = (bid & 7) * cpx + (bid >> 3);
  const int bm = swz % MB;
  const int bn = (swz / MB) % NB;
  const int z  = swz / (MB * NB);
  const int lane = tid & 63, w = tid >> 6;
  const int wm = w >> 1, wn = w & 1;
  const int lrow = lane & 15, lk = lane >> 4;
  const int row0 = bm * 128;

  const int lr = lane >> 3;
  const int lc = lane & 7;
  const int srcb = ((lc ^ lr) << 4);
  const unsigned char* Ab = (const unsigned char*)Hin + (size_t)z * Mz * (K * 2);
  const unsigned char* Wb = (const unsigned char*)W + (size_t)z * N * (K * 2);
  const int ar0 = row0 + w * 32 + lr;
  const int br0 = bn * 128 + w * 32 + lr;
  const unsigned char* aP0 = Ab + (size_t)ar0 * (K * 2) + srcb;
  const unsigned char* bP0 = Wb + (size_t)br0 * (K * 2) + srcb;

  f32x4 acc[4][4];
#pragma unroll
  for (int m = 0; m < 4; ++m)
#pragma unroll
    for (int n = 0; n < 4; ++n) acc[m][n] = {0.f, 0.f, 0.f, 0.f};

  for (int k0b = 0; k0b < K * 2; k0b += 128) {
    __syncthreads();
#pragma unroll
    for (int i = 0; i < 4; ++i) {
      unsigned ldsoff = (unsigned)(w * 32 + 8 * i) * 128u;
      gload16(aP0 + (size_t)i * 8 * (K * 2) + k0b, sA + ldsoff);
      gload16(bP0 + (size_t)i * 8 * (K * 2) + k0b, sB + ldsoff);
    }
    __syncthreads();
#pragma unroll
    for (int ks = 0; ks < 2; ++ks) {
      const int swb = (((ks * 4 + lk) ^ (lrow & 7)) << 4);
      bf16x8 av[4], bv[4];
#pragma unroll
      for (int m = 0; m < 4; ++m)
        av[m] = *(const bf16x8*)(sA + (wm * 64 + m * 16 + lrow) * 128 + swb);
#pragma unroll
      for (int n = 0; n < 4; ++n)
        bv[n] = *(const bf16x8*)(sB + (wn * 64 + n * 16 + lrow) * 128 + swb);
#pragma unroll
      for (int m = 0; m < 4; ++m)
#pragma unroll
        for (int n = 0; n < 4; ++n)
          acc[m][n] = __builtin_amdgcn_mfma_f32_16x16x32_bf16(av[m], bv[n], acc[m][n], 0, 0, 0);
    }
  }
#pragma unroll
  for (int n = 0; n < 4; ++n) {
    int col = bn * 128 + wn * 64 + n * 16 + lrow;
#pragma unroll
    for (int m = 0; m < 4; ++m) {
#pragma unroll
      for (int j = 0; j < 4; ++j) {
        int rl = wm * 64 + m * 16 + lk * 4 + j;
        Out[(size_t)(row0 + rl) * Dn + col] = acc[m][n][j];
      }
    }
  }
}

// expert down, fat N-tile: BM=128, BN=256, K=Fn, scatter atomicAdd*score
__global__ __launch_bounds__(256, 2) void kdown256(
    const unsigned short* __restrict__ Hin, const unsigned short* __restrict__ W,
    const float* __restrict__ bias, const int* __restrict__ idsg,
    const float* __restrict__ scg, float* __restrict__ Out) {
  constexpr int K = Fn;
  constexpr int N = Dn;
  constexpr int MB = CAPn / 128;   // 8
  constexpr int NB = Dn / 256;     // 4
  __shared__ alignas(16) unsigned char sA[16384];
  __shared__ alignas(16) unsigned char sB[32768];
  __shared__ int sIds[128];
  __shared__ float sSc[128];
  const int tid = threadIdx.x;
  const int bid = blockIdx.x;
  const int cpx = gridDim.x >> 3;
  const int swz = (bid & 7) * cpx + (bid >> 3);
  const int bm = swz % MB;
  const int bn = (swz / MB) % NB;
  const int z  = swz / (MB * NB);
  const int lane = tid & 63, w = tid >> 6;
  const int wm = w >> 1, wn = w & 1;
  const int lrow = lane & 15, lk = lane >> 4;
  const int row0 = bm * 128;

  if (tid < 128) {
    sIds[tid] = idsg[z * CAPn + row0 + tid];
    sSc[tid] = scg[z * CAPn + row0 + tid];
  }
  __syncthreads();

  const int lr = lane >> 3;
  const int lc = lane & 7;
  const int srcb = ((lc ^ lr) << 4);
  const unsigned char* Ab = (const unsigned char*)Hin + (size_t)z * CAPn * (K * 2);
  const unsigned char* Wb = (const unsigned char*)W + (size_t)z * N * (K * 2);
  const int ar0 = row0 + w * 32 + lr;
  const int br0 = bn * 256 + w * 64 + lr;
  const unsigned char* aP0 = Ab + (size_t)ar0 * (K * 2) + srcb;
  const unsigned char* bP0 = Wb + (size_t)br0 * (K * 2) + srcb;

  f32x4 acc[4][8];
#pragma unroll
  for (int m = 0; m < 4; ++m)
#pragma unroll
    for (int n = 0; n < 8; ++n) acc[m][n] = {0.f, 0.f, 0.f, 0.f};

  for (int k0b = 0; k0b < K * 2; k0b += 128) {
    __syncthreads();
#pragma unroll
    for (int i = 0; i < 4; ++i)
      gload16(aP0 + (size_t)i * 8 * (K * 2) + k0b,
              sA + (unsigned)(w * 32 + 8 * i) * 128u);
#pragma unroll
    for (int i = 0; i < 8; ++i)
      gload16(bP0 + (size_t)i * 8 * (K * 2) + k0b,
              sB + (unsigned)(w * 64 + 8 * i) * 128u);
    __syncthreads();
#pragma unroll
    for (int ks = 0; ks < 2; ++ks) {
      const int swb = (((ks * 4 + lk) ^ (lrow & 7)) << 4);
      bf16x8 av[4], bv[8];
#pragma unroll
      for (int m = 0; m < 4; ++m)
        av[m] = *(const bf16x8*)(sA + (wm * 64 + m * 16 + lrow) * 128 + swb);
#pragma unroll
      for (int n = 0; n < 8; ++n)
        bv[n] = *(const bf16x8*)(sB + (wn * 128 + n * 16 + lrow) * 128 + swb);
#pragma unroll
      for (int m = 0; m < 4; ++m)
#pragma unroll
        for (int n = 0; n < 8; ++n)
          acc[m][n] = __builtin_amdgcn_mfma_f32_16x16x32_bf16(av[m], bv[n], acc[m][n], 0, 0, 0);
    }
  }
#pragma unroll
  for (int n = 0; n < 8; ++n) {
    int col = bn * 256 + wn * 128 + n * 16 + lrow;
    float bvv = bias[(size_t)z * N + col];
#pragma unroll
    for (int m = 0; m < 4; ++m) {
#pragma unroll
      for (int j = 0; j < 4; ++j) {
        int rl = wm * 64 + m * 16 + lk * 4 + j;
        atomicAdd(Out + (size_t)sIds[rl] * Dn + col, sSc[rl] * (acc[m][n][j] + bvv));
      }
    }
  }
}

extern "C" void kernel_launch(void* const* d_in, const int* in_sizes, int n_in,
                              void* d_out, int out_size, void* d_ws, size_t ws_size,
                              hipStream_t stream) {
  const float* x      = (const float*)d_in[0];
  const float* gate_w = (const float*)d_in[1];
  const float* up_w   = (const float*)d_in[2];
  const float* up_b   = (const float*)d_in[3];
  const float* gw     = (const float*)d_in[4];
  const float* gb     = (const float*)d_in[5];
  const float* down_w = (const float*)d_in[6];
  const float* down_b = (const float*)d_in[7];
  const float* shg    = (const float*)d_in[8];
  const float* shu    = (const float*)d_in[9];
  const float* shd    = (const float*)d_in[10];
  float* out = (float*)d_out;

  const size_t H_BYTES  = (size_t)En * CAPn * Fn * 2;   // 134 MiB
  const size_t XB_BYTES = (size_t)Tn * Dn * 2;          // 16 MiB
  const size_t WE_BYTES = (size_t)En * Fn * Dn * 2;     // 128 MiB each
  const size_t SH_BYTES = (size_t)SHn * Dn * 2;         // 4 MiB each
  const size_t SC_BYTES = (size_t)En * Tn * 4;
  const size_t ID_BYTES = (size_t)En * CAPn * 4;
  const size_t need = H_BYTES + XB_BYTES + 3 * WE_BYTES + 3 * SH_BYTES +
                      SC_BYTES + 2 * ID_BYTES;
  if (ws_size < need) return;

  char* p = (char*)d_ws;
  unsigned short* H    = (unsigned short*)p; p += H_BYTES;
  unsigned short* xb   = (unsigned short*)p; p += XB_BYTES;
  unsigned short* upb  = (unsigned short*)p; p += WE_BYTES;
  unsigned short* gwb  = (unsigned short*)p; p += WE_BYTES;
  unsigned short* dwb  = (unsigned short*)p; p += WE_BYTES;
  unsigned short* shgb = (unsigned short*)p; p += SH_BYTES;
  unsigned short* shub = (unsigned short*)p; p += SH_BYTES;
  unsigned short* shdb = (unsigned short*)p; p += SH_BYTES;
  float* scores = (float*)p; p += SC_BYTES;
  int* ids      = (int*)p;  p += ID_BYTES;
  float* osc    = (float*)p;

  // K1: scores + x->bf16 + all weight converts (2048 full-occupancy conv blocks)
  kscores_cvt<<<Tn + 2048, 256, 0, stream>>>(x, gate_w, scores, xb,
                                             up_w, upb, gw, gwb, down_w, dwb,
                                             shg, shgb, shu, shub, shd, shdb);
  // K2: routing
  kselect<<<En, 256, 0, stream>>>(scores, ids, osc);

  // K3: shared GLU
  kglu_bf<false><<<(Tn / 128) * (SHn / 128), 256, 0, stream>>>(
      xb, nullptr, shgb, shub, nullptr, nullptr, H, SHn, Tn, Tn / 128, SHn / 128);

  // K4: shared down (dense store covers all of d_out)
  kdown_bf<SHn><<<(Tn / 128) * (Dn / 128), 256, 0, stream>>>(
      H, shdb, out, Tn, Tn / 128, Dn / 128);

  // K5: expert GLU
  kglu_bf<true><<<(CAPn / 128) * (Fn / 128) * En, 256, 0, stream>>>(
      xb, ids, gwb, upb, gb, up_b, H, Fn, CAPn, CAPn / 128, Fn / 128);

  // K6: expert down, fat-N tile (512 blocks = 2/CU, one slot-round)
  kdown256<<<(CAPn / 128) * (Dn / 256) * En, 256, 0, stream>>>(
      H, dwb, down_b, ids, osc, out);
}

// Round 16
// 925.922 us; speedup vs baseline: 1.0515x; 1.0515x over previous
//
#include <hip/hip_runtime.h>
#include <hip/hip_bf16.h>

#define Tn 8192
#define Dn 1024
#define Fn 4096
#define SHn 2048
#define En 16
#define CAPn 1024

typedef __bf16 bf16_t;
typedef bf16_t bf16x8 __attribute__((ext_vector_type(8)));
typedef float f32x4 __attribute__((ext_vector_type(4)));

__device__ __forceinline__ unsigned short f2bf(float f) {
  unsigned int u = __builtin_bit_cast(unsigned int, f);
  u += 0x7FFFu + ((u >> 16) & 1u);
  return (unsigned short)(u >> 16);
}
__device__ __forceinline__ unsigned int pack2(float a, float b) {
  return (unsigned int)f2bf(a) | ((unsigned int)f2bf(b) << 16);
}

__device__ __forceinline__ void gload16(const void* g, void* l) {
  __builtin_amdgcn_global_load_lds(
      (const __attribute__((address_space(1))) unsigned int*)g,
      (__attribute__((address_space(3))) unsigned int*)l, 16, 0, 0);
}

// simple grid-stride fp32->bf16 over up to two tensors (small shared tensors)
__device__ __forceinline__ void conv_blocks(int cb, int ncb, int tid,
                                            const float* s1, unsigned short* d1, int n1,
                                            const float* s2, unsigned short* d2, int n2) {
  const int tot = n1 + n2;
  for (int i = cb * 256 + tid; i < tot; i += ncb * 256) {
    const float4* sv; uint4* dv; int j;
    if (i < n1) { j = i; sv = (const float4*)s1; dv = (uint4*)d1; }
    else        { j = i - n1; sv = (const float4*)s2; dv = (uint4*)d2; }
    float4 a = sv[2 * j], b = sv[2 * j + 1];
    dv[j] = uint4{ pack2(a.x, a.y), pack2(a.z, a.w), pack2(b.x, b.y), pack2(b.z, b.w) };
  }
}

// 4-way-ILP grid-stride fp32->bf16 (single tensor) for fused conv blocks
__device__ __forceinline__ void conv4(int cb, int ncb, int tid,
                                      const float* __restrict__ s,
                                      unsigned short* __restrict__ d, int n8) {
  const int step = ncb * 256;
  const float4* sv = (const float4*)s;
  uint4* dv = (uint4*)d;
  for (int i = cb * 256 + tid; i < n8; i += 4 * step) {
    const int i1 = i + step, i2 = i + 2 * step, i3 = i + 3 * step;
    const bool v1 = i1 < n8, v2 = i2 < n8, v3 = i3 < n8;
    float4 a0 = sv[2 * i], b0 = sv[2 * i + 1];
    float4 a1{}, b1{}, a2{}, b2{}, a3{}, b3{};
    if (v1) { a1 = sv[2 * i1]; b1 = sv[2 * i1 + 1]; }
    if (v2) { a2 = sv[2 * i2]; b2 = sv[2 * i2 + 1]; }
    if (v3) { a3 = sv[2 * i3]; b3 = sv[2 * i3 + 1]; }
    dv[i] = uint4{ pack2(a0.x, a0.y), pack2(a0.z, a0.w), pack2(b0.x, b0.y), pack2(b0.z, b0.w) };
    if (v1) dv[i1] = uint4{ pack2(a1.x, a1.y), pack2(a1.z, a1.w), pack2(b1.x, b1.y), pack2(b1.z, b1.w) };
    if (v2) dv[i2] = uint4{ pack2(a2.x, a2.y), pack2(a2.z, a2.w), pack2(b2.x, b2.y), pack2(b2.z, b2.w) };
    if (v3) dv[i3] = uint4{ pack2(a3.x, a3.y), pack2(a3.z, a3.w), pack2(b3.x, b3.y), pack2(b3.z, b3.w) };
  }
}

// ---------------- gate scores (4 tokens/block) + x->bf16 + shared-weight converts ----------------
// blocks [0, Tn/4): 4 tokens each. [Tn/4, Tn/4+256): shared conv.
__global__ __launch_bounds__(256) void kscores_cvt(
    const float* __restrict__ x, const float* __restrict__ gw,
    float* __restrict__ sc, unsigned short* __restrict__ xb,
    const float* __restrict__ shg, unsigned short* __restrict__ shgb,
    const float* __restrict__ shu, unsigned short* __restrict__ shub,
    const float* __restrict__ shd, unsigned short* __restrict__ shdb) {
  __shared__ float sx[Dn];
  const int tid = threadIdx.x;
  constexpr int NSB = Tn / 4;   // 2048 score blocks
  if (blockIdx.x >= NSB) {
    const int cb = blockIdx.x - NSB, ncb = gridDim.x - NSB;
    constexpr int nsh = SHn * Dn / 8;
    conv_blocks(cb, ncb, tid, shg, shgb, nsh, shu, shub, nsh);
    conv_blocks(cb, ncb, tid, shd, shdb, nsh, nullptr, nullptr, 0);
    return;
  }
  const int e = tid >> 4, kl = tid & 15;
  const float4* w = (const float4*)(gw + e * Dn);
#pragma unroll 1
  for (int t4 = 0; t4 < 4; ++t4) {
    const int tok = blockIdx.x * 4 + t4;
    float4 v = ((const float4*)(x + (size_t)tok * Dn))[tid];
    ((float4*)sx)[tid] = v;
    ((uint2*)(xb + (size_t)tok * Dn))[tid] = uint2{ pack2(v.x, v.y), pack2(v.z, v.w) };
    __syncthreads();
    const float4* xv = (const float4*)sx;
    float acc = 0.f;
#pragma unroll
    for (int j = 0; j < 16; ++j) {
      float4 a = w[kl + 16 * j], b = xv[kl + 16 * j];
      acc += a.x * b.x + a.y * b.y + a.z * b.z + a.w * b.w;
    }
#pragma unroll
    for (int off = 8; off; off >>= 1) acc += __shfl_xor(acc, off, 64);
    if (kl == 0) sc[(size_t)e * Tn + tok] = 1.f / (1.f + expf(-acc));
    __syncthreads();
  }
}

// ---------------- per-expert top-CAP radix select (ties: lowest index) ----------------
__global__ __launch_bounds__(256) void kselect(const float* __restrict__ scores,
                                               int* __restrict__ ids,
                                               float* __restrict__ oscore) {
  __shared__ unsigned int keys[Tn];
  __shared__ unsigned int hist[256];
  __shared__ unsigned int sh_prefix, sh_k, sh_cnt, sh_eq;
  __shared__ int eqlist[1024];
  const int tid = threadIdx.x, e = blockIdx.x;
  const float* row = scores + (size_t)e * Tn;
  for (int i = 0; i < Tn / 256; ++i)
    keys[tid + i * 256] = __float_as_uint(row[tid + i * 256]);
  if (tid == 0) { sh_prefix = 0u; sh_k = CAPn; }
  __syncthreads();
  for (int shift = 24; shift >= 0; shift -= 8) {
    hist[tid] = 0u;
    __syncthreads();
    unsigned int prefix = sh_prefix;
    unsigned int mask = (shift == 24) ? 0u : (0xFFFFFFFFu << (shift + 8));
    for (int i = 0; i < Tn / 256; ++i) {
      unsigned int kk = keys[tid + i * 256];
      if ((kk & mask) == prefix) atomicAdd(&hist[(kk >> shift) & 255], 1u);
    }
    __syncthreads();
    if (tid == 0) {
      unsigned int k = sh_k, c = 0; int b;
      for (b = 255; b >= 0; --b) { c += hist[b]; if (c >= k) break; }
      sh_k = k - (c - hist[b]);
      sh_prefix = prefix | ((unsigned int)b << shift);
    }
    __syncthreads();
  }
  const unsigned int thr = sh_prefix;
  if (tid == 0) { sh_cnt = 0u; sh_eq = 0u; }
  __syncthreads();
  const int base = e * CAPn;
  for (int i = 0; i < Tn / 256; ++i) {
    int t = tid + i * 256;
    unsigned int kk = keys[t];
    if (kk > thr) {
      unsigned int p = atomicAdd(&sh_cnt, 1u);
      ids[base + p] = t;
      oscore[base + p] = __uint_as_float(kk);
    } else if (kk == thr) {
      unsigned int p = atomicAdd(&sh_eq, 1u);
      if (p < 1024u) eqlist[p] = t;
    }
  }
  __syncthreads();
  if (tid == 0) {
    int need = CAPn - (int)sh_cnt;
    int m = (int)sh_eq; if (m > 1024) m = 1024;
    for (int j = 0; j < need; ++j) {
      int best = 1 << 30, bi = 0;
      for (int i2 = 0; i2 < m; ++i2)
        if (eqlist[i2] < best) { best = eqlist[i2]; bi = i2; }
      eqlist[bi] = 1 << 30;
      ids[base + (int)sh_cnt + j] = best;
      oscore[base + (int)sh_cnt + j] = __uint_as_float(thr);
    }
  }
}

// =====================================================================
// Proven round-2 GEMMs (2-phase, 128x128, 16x16x32 MFMA, (256,2)) with
// STRIPED conv blocks (round-10/14 pattern).
// =====================================================================

// GLU: H = bf16( silu(A@Wg^T + bg) * (A@Wu^T + bu) ), K = Dn
template <bool GATHER>
__global__ __launch_bounds__(256, 2) void kglu_bf(
    const unsigned short* __restrict__ X, const int* __restrict__ idsg,
    const unsigned short* __restrict__ Wg, const unsigned short* __restrict__ Wu,
    const float* __restrict__ biasg, const float* __restrict__ biasu,
    unsigned short* __restrict__ H, int N, int Mz, int MB, int NB,
    int gemmN, int convP,
    const float* __restrict__ cS1, unsigned short* __restrict__ cD1, int cn1) {
  constexpr int K = Dn;
  __shared__ alignas(16) unsigned char sA[16384];
  __shared__ alignas(16) unsigned char sB1[16384];
  __shared__ alignas(16) unsigned char sB2[16384];
  __shared__ int sIds[128];
  const int tid = threadIdx.x;
  const int bid = blockIdx.x;
  if (convP && (bid % convP) == convP - 1) {
    conv4(bid / convP, gridDim.x - gemmN, tid, cS1, cD1, cn1);
    return;
  }
  const int gbid = convP ? (bid - bid / convP) : bid;
  const int cpx = gemmN >> 3;
  const int swz = (gbid & 7) * cpx + (gbid >> 3);
  const int bm = swz % MB;
  const int bn = (swz / MB) % NB;
  const int z  = swz / (MB * NB);
  const int lane = tid & 63, w = tid >> 6;
  const int wm = w >> 1, wn = w & 1;
  const int lrow = lane & 15, lk = lane >> 4;
  const int row0 = bm * 128;

  if (tid < 128) sIds[tid] = GATHER ? idsg[z * CAPn + row0 + tid] : (row0 + tid);
  __syncthreads();

  const int lr = lane >> 3;
  const int lc = lane & 7;
  const int srcb = ((lc ^ lr) << 4);
  const unsigned char* Xb = (const unsigned char*)X;
  const unsigned char* Gb = (const unsigned char*)Wg + (size_t)z * N * (K * 2);
  const unsigned char* Ub = (const unsigned char*)Wu + (size_t)z * N * (K * 2);
  const unsigned char* aP[4];
#pragma unroll
  for (int i = 0; i < 4; ++i) {
    int ar = w * 32 + 8 * i + lr;
    aP[i] = Xb + (size_t)sIds[ar] * (K * 2) + srcb;
  }
  const int br0 = bn * 128 + w * 32 + lr;
  const unsigned char* gP0 = Gb + (size_t)br0 * (K * 2) + srcb;
  const unsigned char* uP0 = Ub + (size_t)br0 * (K * 2) + srcb;

  f32x4 accG[4][4], accU[4][4];
#pragma unroll
  for (int m = 0; m < 4; ++m)
#pragma unroll
    for (int n = 0; n < 4; ++n) {
      accG[m][n] = {0.f, 0.f, 0.f, 0.f};
      accU[m][n] = {0.f, 0.f, 0.f, 0.f};
    }

  for (int k0b = 0; k0b < K * 2; k0b += 128) {
    __syncthreads();
#pragma unroll
    for (int i = 0; i < 4; ++i) {
      unsigned ldsoff = (unsigned)(w * 32 + 8 * i) * 128u;
      gload16(aP[i] + k0b, sA + ldsoff);
      gload16(gP0 + (size_t)i * 8 * (K * 2) + k0b, sB1 + ldsoff);
      gload16(uP0 + (size_t)i * 8 * (K * 2) + k0b, sB2 + ldsoff);
    }
    __syncthreads();
#pragma unroll
    for (int ks = 0; ks < 2; ++ks) {
      const int swb = (((ks * 4 + lk) ^ (lrow & 7)) << 4);
      bf16x8 av[4], gv[4], uv[4];
#pragma unroll
      for (int m = 0; m < 4; ++m)
        av[m] = *(const bf16x8*)(sA + (wm * 64 + m * 16 + lrow) * 128 + swb);
#pragma unroll
      for (int n = 0; n < 4; ++n) {
        gv[n] = *(const bf16x8*)(sB1 + (wn * 64 + n * 16 + lrow) * 128 + swb);
        uv[n] = *(const bf16x8*)(sB2 + (wn * 64 + n * 16 + lrow) * 128 + swb);
      }
#pragma unroll
      for (int m = 0; m < 4; ++m)
#pragma unroll
        for (int n = 0; n < 4; ++n) {
          accG[m][n] = __builtin_amdgcn_mfma_f32_16x16x32_bf16(av[m], gv[n], accG[m][n], 0, 0, 0);
          accU[m][n] = __builtin_amdgcn_mfma_f32_16x16x32_bf16(av[m], uv[n], accU[m][n], 0, 0, 0);
        }
    }
  }
#pragma unroll
  for (int n = 0; n < 4; ++n) {
    int col = bn * 128 + wn * 64 + n * 16 + lrow;
    float bg = biasg ? biasg[(size_t)z * N + col] : 0.f;
    float bu = biasu ? biasu[(size_t)z * N + col] : 0.f;
#pragma unroll
    for (int m = 0; m < 4; ++m) {
#pragma unroll
      for (int j = 0; j < 4; ++j) {
        float g = accG[m][n][j] + bg;
        float u = accU[m][n][j] + bu;
        float h = g / (1.f + __expf(-g)) * u;
        int row = row0 + wm * 64 + m * 16 + lk * 4 + j;
        H[(size_t)z * Mz * N + (size_t)row * N + col] = f2bf(h);
      }
    }
  }
}

// down (shared): Out = A@W^T dense store, BM=128 BN=128, K = SHn
template <int K, bool SCATTER>
__global__ __launch_bounds__(256, 2) void kdown_bf(
    const unsigned short* __restrict__ Hin, const unsigned short* __restrict__ W,
    const float* __restrict__ bias, const int* __restrict__ idsg,
    const float* __restrict__ scg, float* __restrict__ Out, int Mz, int MB, int NB,
    int gemmN, int convP,
    const float* __restrict__ cS1, unsigned short* __restrict__ cD1, int cn1) {
  constexpr int N = Dn;
  __shared__ alignas(16) unsigned char sA[16384];
  __shared__ alignas(16) unsigned char sB[16384];
  __shared__ int sIds[128];
  __shared__ float sSc[128];
  const int tid = threadIdx.x;
  const int bid = blockIdx.x;
  if (convP && (bid % convP) == convP - 1) {
    conv4(bid / convP, gridDim.x - gemmN, tid, cS1, cD1, cn1);
    return;
  }
  const int gbid = convP ? (bid - bid / convP) : bid;
  const int cpx = gemmN >> 3;
  const int swz = (gbid & 7) * cpx + (gbid >> 3);
  const int bm = swz % MB;
  const int bn = (swz / MB) % NB;
  const int z  = swz / (MB * NB);
  const int lane = tid & 63, w = tid >> 6;
  const int wm = w >> 1, wn = w & 1;
  const int lrow = lane & 15, lk = lane >> 4;
  const int row0 = bm * 128;

  if (SCATTER && tid < 128) {
    sIds[tid] = idsg[z * CAPn + row0 + tid];
    sSc[tid] = scg[z * CAPn + row0 + tid];
  }
  __syncthreads();

  const int lr = lane >> 3;
  const int lc = lane & 7;
  const int srcb = ((lc ^ lr) << 4);
  const unsigned char* Ab = (const unsigned char*)Hin + (size_t)z * Mz * (K * 2);
  const unsigned char* Wb = (const unsigned char*)W + (size_t)z * N * (K * 2);
  const int ar0 = row0 + w * 32 + lr;
  const int br0 = bn * 128 + w * 32 + lr;
  const unsigned char* aP0 = Ab + (size_t)ar0 * (K * 2) + srcb;
  const unsigned char* bP0 = Wb + (size_t)br0 * (K * 2) + srcb;

  f32x4 acc[4][4];
#pragma unroll
  for (int m = 0; m < 4; ++m)
#pragma unroll
    for (int n = 0; n < 4; ++n) acc[m][n] = {0.f, 0.f, 0.f, 0.f};

  for (int k0b = 0; k0b < K * 2; k0b += 128) {
    __syncthreads();
#pragma unroll
    for (int i = 0; i < 4; ++i) {
      unsigned ldsoff = (unsigned)(w * 32 + 8 * i) * 128u;
      gload16(aP0 + (size_t)i * 8 * (K * 2) + k0b, sA + ldsoff);
      gload16(bP0 + (size_t)i * 8 * (K * 2) + k0b, sB + ldsoff);
    }
    __syncthreads();
#pragma unroll
    for (int ks = 0; ks < 2; ++ks) {
      const int swb = (((ks * 4 + lk) ^ (lrow & 7)) << 4);
      bf16x8 av[4], bv[4];
#pragma unroll
      for (int m = 0; m < 4; ++m)
        av[m] = *(const bf16x8*)(sA + (wm * 64 + m * 16 + lrow) * 128 + swb);
#pragma unroll
      for (int n = 0; n < 4; ++n)
        bv[n] = *(const bf16x8*)(sB + (wn * 64 + n * 16 + lrow) * 128 + swb);
#pragma unroll
      for (int m = 0; m < 4; ++m)
#pragma unroll
        for (int n = 0; n < 4; ++n)
          acc[m][n] = __builtin_amdgcn_mfma_f32_16x16x32_bf16(av[m], bv[n], acc[m][n], 0, 0, 0);
    }
  }
#pragma unroll
  for (int n = 0; n < 4; ++n) {
    int col = bn * 128 + wn * 64 + n * 16 + lrow;
    float bvv = bias ? bias[(size_t)z * N + col] : 0.f;
#pragma unroll
    for (int m = 0; m < 4; ++m) {
#pragma unroll
      for (int j = 0; j < 4; ++j) {
        int rl = wm * 64 + m * 16 + lk * 4 + j;
        float v = acc[m][n][j] + bvv;
        if (SCATTER) {
          atomicAdd(Out + (size_t)sIds[rl] * Dn + col, sSc[rl] * v);
        } else {
          Out[(size_t)(row0 + rl) * Dn + col] = v;
        }
      }
    }
  }
}

// expert down, fat N-tile: BM=128, BN=256, K=Fn, scatter atomicAdd*score
__global__ __launch_bounds__(256, 2) void kdown256(
    const unsigned short* __restrict__ Hin, const unsigned short* __restrict__ W,
    const float* __restrict__ bias, const int* __restrict__ idsg,
    const float* __restrict__ scg, float* __restrict__ Out) {
  constexpr int K = Fn;
  constexpr int N = Dn;
  constexpr int MB = CAPn / 128;   // 8
  constexpr int NB = Dn / 256;     // 4
  __shared__ alignas(16) unsigned char sA[16384];
  __shared__ alignas(16) unsigned char sB[32768];
  __shared__ int sIds[128];
  __shared__ float sSc[128];
  const int tid = threadIdx.x;
  const int bid = blockIdx.x;
  const int cpx = gridDim.x >> 3;
  const int swz = (bid & 7) * cpx + (bid >> 3);
  const int bm = swz % MB;
  const int bn = (swz / MB) % NB;
  const int z  = swz / (MB * NB);
  const int lane = tid & 63, w = tid >> 6;
  const int wm = w >> 1, wn = w & 1;
  const int lrow = lane & 15, lk = lane >> 4;
  const int row0 = bm * 128;

  if (tid < 128) {
    sIds[tid] = idsg[z * CAPn + row0 + tid];
    sSc[tid] = scg[z * CAPn + row0 + tid];
  }
  __syncthreads();

  const int lr = lane >> 3;
  const int lc = lane & 7;
  const int srcb = ((lc ^ lr) << 4);
  const unsigned char* Ab = (const unsigned char*)Hin + (size_t)z * CAPn * (K * 2);
  const unsigned char* Wb = (const unsigned char*)W + (size_t)z * N * (K * 2);
  const int ar0 = row0 + w * 32 + lr;
  const int br0 = bn * 256 + w * 64 + lr;
  const unsigned char* aP0 = Ab + (size_t)ar0 * (K * 2) + srcb;
  const unsigned char* bP0 = Wb + (size_t)br0 * (K * 2) + srcb;

  f32x4 acc[4][8];
#pragma unroll
  for (int m = 0; m < 4; ++m)
#pragma unroll
    for (int n = 0; n < 8; ++n) acc[m][n] = {0.f, 0.f, 0.f, 0.f};

  for (int k0b = 0; k0b < K * 2; k0b += 128) {
    __syncthreads();
#pragma unroll
    for (int i = 0; i < 4; ++i)
      gload16(aP0 + (size_t)i * 8 * (K * 2) + k0b,
              sA + (unsigned)(w * 32 + 8 * i) * 128u);
#pragma unroll
    for (int i = 0; i < 8; ++i)
      gload16(bP0 + (size_t)i * 8 * (K * 2) + k0b,
              sB + (unsigned)(w * 64 + 8 * i) * 128u);
    __syncthreads();
#pragma unroll
    for (int ks = 0; ks < 2; ++ks) {
      const int swb = (((ks * 4 + lk) ^ (lrow & 7)) << 4);
      bf16x8 av[4], bv[8];
#pragma unroll
      for (int m = 0; m < 4; ++m)
        av[m] = *(const bf16x8*)(sA + (wm * 64 + m * 16 + lrow) * 128 + swb);
#pragma unroll
      for (int n = 0; n < 8; ++n)
        bv[n] = *(const bf16x8*)(sB + (wn * 128 + n * 16 + lrow) * 128 + swb);
#pragma unroll
      for (int m = 0; m < 4; ++m)
#pragma unroll
        for (int n = 0; n < 8; ++n)
          acc[m][n] = __builtin_amdgcn_mfma_f32_16x16x32_bf16(av[m], bv[n], acc[m][n], 0, 0, 0);
    }
  }
#pragma unroll
  for (int n = 0; n < 8; ++n) {
    int col = bn * 256 + wn * 128 + n * 16 + lrow;
    float bvv = bias[(size_t)z * N + col];
#pragma unroll
    for (int m = 0; m < 4; ++m) {
#pragma unroll
      for (int j = 0; j < 4; ++j) {
        int rl = wm * 64 + m * 16 + lk * 4 + j;
        atomicAdd(Out + (size_t)sIds[rl] * Dn + col, sSc[rl] * (acc[m][n][j] + bvv));
      }
    }
  }
}

extern "C" void kernel_launch(void* const* d_in, const int* in_sizes, int n_in,
                              void* d_out, int out_size, void* d_ws, size_t ws_size,
                              hipStream_t stream) {
  const float* x      = (const float*)d_in[0];
  const float* gate_w = (const float*)d_in[1];
  const float* up_w   = (const float*)d_in[2];
  const float* up_b   = (const float*)d_in[3];
  const float* gw     = (const float*)d_in[4];
  const float* gb     = (const float*)d_in[5];
  const float* down_w = (const float*)d_in[6];
  const float* down_b = (const float*)d_in[7];
  const float* shg    = (const float*)d_in[8];
  const float* shu    = (const float*)d_in[9];
  const float* shd    = (const float*)d_in[10];
  float* out = (float*)d_out;

  const size_t H_BYTES  = (size_t)En * CAPn * Fn * 2;   // 134 MiB
  const size_t XB_BYTES = (size_t)Tn * Dn * 2;          // 16 MiB
  const size_t WE_BYTES = (size_t)En * Fn * Dn * 2;     // 128 MiB each
  const size_t SH_BYTES = (size_t)SHn * Dn * 2;         // 4 MiB each
  const size_t SC_BYTES = (size_t)En * Tn * 4;
  const size_t ID_BYTES = (size_t)En * CAPn * 4;
  const size_t need = H_BYTES + XB_BYTES + 3 * WE_BYTES + 3 * SH_BYTES +
                      SC_BYTES + 2 * ID_BYTES;
  if (ws_size < need) return;

  char* p = (char*)d_ws;
  unsigned short* H    = (unsigned short*)p; p += H_BYTES;
  unsigned short* xb   = (unsigned short*)p; p += XB_BYTES;
  unsigned short* upb  = (unsigned short*)p; p += WE_BYTES;
  unsigned short* gwb  = (unsigned short*)p; p += WE_BYTES;
  unsigned short* dwb  = (unsigned short*)p; p += WE_BYTES;
  unsigned short* shgb = (unsigned short*)p; p += SH_BYTES;
  unsigned short* shub = (unsigned short*)p; p += SH_BYTES;
  unsigned short* shdb = (unsigned short*)p; p += SH_BYTES;
  float* scores = (float*)p; p += SC_BYTES;
  int* ids      = (int*)p;  p += ID_BYTES;
  float* osc    = (float*)p;

  constexpr int NWE8 = En * Fn * Dn / 8;   // bf16x8 chunks per expert-weight tensor

  // K1: scores (4 tok/block) + x->bf16 + shared-weight converts
  kscores_cvt<<<Tn / 4 + 256, 256, 0, stream>>>(x, gate_w, scores, xb,
                                                shg, shgb, shu, shub, shd, shdb);
  // K2: routing
  kselect<<<En, 256, 0, stream>>>(scores, ids, osc);

  // K3: shared GLU (1024 GEMM) + up_w conv striped 1:1 (P=2, 1024 conv)
  kglu_bf<false><<<1024 + 1024, 256, 0, stream>>>(
      xb, nullptr, shgb, shub, nullptr, nullptr, H, SHn, Tn, Tn / 128, SHn / 128,
      1024, 2, up_w, upb, NWE8);

  // K4: shared down (512 GEMM) + gw conv striped 1:1 (P=2, 512 conv)
  kdown_bf<SHn, false><<<512 + 512, 256, 0, stream>>>(
      H, shdb, nullptr, nullptr, nullptr, out, Tn, Tn / 128, Dn / 128,
      512, 2, gw, gwb, NWE8);

  // K5: expert GLU (4096 GEMM) + down_w conv striped 4:1 (P=5, 1024 conv)
  kglu_bf<true><<<4096 + 1024, 256, 0, stream>>>(
      xb, ids, gwb, upb, gb, up_b, H, Fn, CAPn, CAPn / 128, Fn / 128,
      4096, 5, down_w, dwb, NWE8);

  // K6: expert down, fat-N tile (512 blocks = 2/CU, one slot-round)
  kdown256<<<(CAPn / 128) * (Dn / 256) * En, 256, 0, stream>>>(
      H, dwb, down_b, ids, osc, out);
}

// Round 17
// 888.434 us; speedup vs baseline: 1.0959x; 1.0422x over previous
//
#include <hip/hip_runtime.h>
#include <hip/hip_bf16.h>

#define Tn 8192
#define Dn 1024
#define Fn 4096
#define SHn 2048
#define En 16
#define CAPn 1024

typedef __bf16 bf16_t;
typedef bf16_t bf16x8 __attribute__((ext_vector_type(8)));
typedef float f32x4 __attribute__((ext_vector_type(4)));

__device__ __forceinline__ unsigned short f2bf(float f) {
  unsigned int u = __builtin_bit_cast(unsigned int, f);
  u += 0x7FFFu + ((u >> 16) & 1u);
  return (unsigned short)(u >> 16);
}
__device__ __forceinline__ unsigned int pack2(float a, float b) {
  return (unsigned int)f2bf(a) | ((unsigned int)f2bf(b) << 16);
}

__device__ __forceinline__ void gload16(const void* g, void* l) {
  __builtin_amdgcn_global_load_lds(
      (const __attribute__((address_space(1))) unsigned int*)g,
      (__attribute__((address_space(3))) unsigned int*)l, 16, 0, 0);
}

// simple grid-stride fp32->bf16 over up to two tensors (small shared tensors)
__device__ __forceinline__ void conv_blocks(int cb, int ncb, int tid,
                                            const float* s1, unsigned short* d1, int n1,
                                            const float* s2, unsigned short* d2, int n2) {
  const int tot = n1 + n2;
  for (int i = cb * 256 + tid; i < tot; i += ncb * 256) {
    const float4* sv; uint4* dv; int j;
    if (i < n1) { j = i; sv = (const float4*)s1; dv = (uint4*)d1; }
    else        { j = i - n1; sv = (const float4*)s2; dv = (uint4*)d2; }
    float4 a = sv[2 * j], b = sv[2 * j + 1];
    dv[j] = uint4{ pack2(a.x, a.y), pack2(a.z, a.w), pack2(b.x, b.y), pack2(b.z, b.w) };
  }
}

// 4-way-ILP grid-stride fp32->bf16 (single tensor) for fused conv blocks
__device__ __forceinline__ void conv4(int cb, int ncb, int tid,
                                      const float* __restrict__ s,
                                      unsigned short* __restrict__ d, int n8) {
  const int step = ncb * 256;
  const float4* sv = (const float4*)s;
  uint4* dv = (uint4*)d;
  for (int i = cb * 256 + tid; i < n8; i += 4 * step) {
    const int i1 = i + step, i2 = i + 2 * step, i3 = i + 3 * step;
    const bool v1 = i1 < n8, v2 = i2 < n8, v3 = i3 < n8;
    float4 a0 = sv[2 * i], b0 = sv[2 * i + 1];
    float4 a1{}, b1{}, a2{}, b2{}, a3{}, b3{};
    if (v1) { a1 = sv[2 * i1]; b1 = sv[2 * i1 + 1]; }
    if (v2) { a2 = sv[2 * i2]; b2 = sv[2 * i2 + 1]; }
    if (v3) { a3 = sv[2 * i3]; b3 = sv[2 * i3 + 1]; }
    dv[i] = uint4{ pack2(a0.x, a0.y), pack2(a0.z, a0.w), pack2(b0.x, b0.y), pack2(b0.z, b0.w) };
    if (v1) dv[i1] = uint4{ pack2(a1.x, a1.y), pack2(a1.z, a1.w), pack2(b1.x, b1.y), pack2(b1.z, b1.w) };
    if (v2) dv[i2] = uint4{ pack2(a2.x, a2.y), pack2(a2.z, a2.w), pack2(b2.x, b2.y), pack2(b2.z, b2.w) };
    if (v3) dv[i3] = uint4{ pack2(a3.x, a3.y), pack2(a3.z, a3.w), pack2(b3.x, b3.y), pack2(b3.z, b3.w) };
  }
}

// per-expert top-CAP radix select over scores[e][*] using a 49664B smem block
__device__ __forceinline__ void do_select(unsigned char* smem, int tid, int e,
                                          const float* __restrict__ scores,
                                          int* __restrict__ ids,
                                          float* __restrict__ oscore) {
  unsigned int* keys = (unsigned int*)smem;                 // 32 KB
  unsigned int* hist = (unsigned int*)(smem + 32768);       // 1 KB
  int* eqlist = (int*)(smem + 33792);                       // 4 KB
  unsigned int* st = (unsigned int*)(smem + 37888);         // prefix,k,cnt,eq
  const float* row = scores + (size_t)e * Tn;
  for (int i = 0; i < Tn / 256; ++i)
    keys[tid + i * 256] = __float_as_uint(row[tid + i * 256]);
  if (tid == 0) { st[0] = 0u; st[1] = CAPn; }
  __syncthreads();
  for (int shift = 24; shift >= 0; shift -= 8) {
    hist[tid] = 0u;
    __syncthreads();
    unsigned int prefix = st[0];
    unsigned int mask = (shift == 24) ? 0u : (0xFFFFFFFFu << (shift + 8));
    for (int i = 0; i < Tn / 256; ++i) {
      unsigned int kk = keys[tid + i * 256];
      if ((kk & mask) == prefix) atomicAdd(&hist[(kk >> shift) & 255], 1u);
    }
    __syncthreads();
    if (tid == 0) {
      unsigned int k = st[1], c = 0; int b;
      for (b = 255; b >= 0; --b) { c += hist[b]; if (c >= k) break; }
      st[1] = k - (c - hist[b]);
      st[0] = prefix | ((unsigned int)b << shift);
    }
    __syncthreads();
  }
  const unsigned int thr = st[0];
  if (tid == 0) { st[2] = 0u; st[3] = 0u; }
  __syncthreads();
  const int base = e * CAPn;
  for (int i = 0; i < Tn / 256; ++i) {
    int t = tid + i * 256;
    unsigned int kk = keys[t];
    if (kk > thr) {
      unsigned int p = atomicAdd(&st[2], 1u);
      ids[base + p] = t;
      oscore[base + p] = __uint_as_float(kk);
    } else if (kk == thr) {
      unsigned int p = atomicAdd(&st[3], 1u);
      if (p < 1024u) eqlist[p] = t;
    }
  }
  __syncthreads();
  if (tid == 0) {
    int need = CAPn - (int)st[2];
    int m = (int)st[3]; if (m > 1024) m = 1024;
    for (int j = 0; j < need; ++j) {
      int best = 1 << 30, bi = 0;
      for (int i2 = 0; i2 < m; ++i2)
        if (eqlist[i2] < best) { best = eqlist[i2]; bi = i2; }
      eqlist[bi] = 1 << 30;
      ids[base + (int)st[2] + j] = best;
      oscore[base + (int)st[2] + j] = __uint_as_float(thr);
    }
  }
}

// ---------------- gate scores (4 tokens/block) + x->bf16 + shared-weight converts ----------------
__global__ __launch_bounds__(256) void kscores_cvt(
    const float* __restrict__ x, const float* __restrict__ gw,
    float* __restrict__ sc, unsigned short* __restrict__ xb,
    const float* __restrict__ shg, unsigned short* __restrict__ shgb,
    const float* __restrict__ shu, unsigned short* __restrict__ shub,
    const float* __restrict__ shd, unsigned short* __restrict__ shdb) {
  __shared__ float sx[Dn];
  const int tid = threadIdx.x;
  constexpr int NSB = Tn / 4;   // 2048 score blocks
  if (blockIdx.x >= NSB) {
    const int cb = blockIdx.x - NSB, ncb = gridDim.x - NSB;
    constexpr int nsh = SHn * Dn / 8;
    conv_blocks(cb, ncb, tid, shg, shgb, nsh, shu, shub, nsh);
    conv_blocks(cb, ncb, tid, shd, shdb, nsh, nullptr, nullptr, 0);
    return;
  }
  const int e = tid >> 4, kl = tid & 15;
  const float4* w = (const float4*)(gw + e * Dn);
#pragma unroll 1
  for (int t4 = 0; t4 < 4; ++t4) {
    const int tok = blockIdx.x * 4 + t4;
    float4 v = ((const float4*)(x + (size_t)tok * Dn))[tid];
    ((float4*)sx)[tid] = v;
    ((uint2*)(xb + (size_t)tok * Dn))[tid] = uint2{ pack2(v.x, v.y), pack2(v.z, v.w) };
    __syncthreads();
    const float4* xv = (const float4*)sx;
    float acc = 0.f;
#pragma unroll
    for (int j = 0; j < 16; ++j) {
      float4 a = w[kl + 16 * j], b = xv[kl + 16 * j];
      acc += a.x * b.x + a.y * b.y + a.z * b.z + a.w * b.w;
    }
#pragma unroll
    for (int off = 8; off; off >>= 1) acc += __shfl_xor(acc, off, 64);
    if (kl == 0) sc[(size_t)e * Tn + tok] = 1.f / (1.f + expf(-acc));
    __syncthreads();
  }
}

// =====================================================================
// Proven round-2 GEMMs (2-phase, 128x128, 16x16x32 MFMA, (256,2)) with
// STRIPED conv blocks + optional SELECT blocks at the front of the grid.
// Single 49664B smem block, same offsets as the separate arrays before.
// =====================================================================

// GLU: H = bf16( silu(A@Wg^T + bg) * (A@Wu^T + bu) ), K = Dn
template <bool GATHER>
__global__ __launch_bounds__(256, 2) void kglu_bf(
    const unsigned short* __restrict__ X, const int* __restrict__ idsg,
    const unsigned short* __restrict__ Wg, const unsigned short* __restrict__ Wu,
    const float* __restrict__ biasg, const float* __restrict__ biasu,
    unsigned short* __restrict__ H, int N, int Mz, int MB, int NB,
    int gemmN, int convP,
    const float* __restrict__ cS1, unsigned short* __restrict__ cD1, int cn1,
    int selN, const float* __restrict__ selSc, int* __restrict__ selIds,
    float* __restrict__ selOsc) {
  constexpr int K = Dn;
  __shared__ alignas(16) unsigned char smem[49664];
  unsigned char* sA  = smem;
  unsigned char* sB1 = smem + 16384;
  unsigned char* sB2 = smem + 32768;
  int* sIds = (int*)(smem + 49152);
  const int tid = threadIdx.x;
  const int bid0 = blockIdx.x;
  if (bid0 < selN) { do_select(smem, tid, bid0, selSc, selIds, selOsc); return; }
  const int bid = bid0 - selN;
  if (convP && (bid % convP) == convP - 1) {
    conv4(bid / convP, gridDim.x - selN - gemmN, tid, cS1, cD1, cn1);
    return;
  }
  const int gbid = convP ? (bid - bid / convP) : bid;
  const int cpx = gemmN >> 3;
  const int swz = (gbid & 7) * cpx + (gbid >> 3);
  const int bm = swz % MB;
  const int bn = (swz / MB) % NB;
  const int z  = swz / (MB * NB);
  const int lane = tid & 63, w = tid >> 6;
  const int wm = w >> 1, wn = w & 1;
  const int lrow = lane & 15, lk = lane >> 4;
  const int row0 = bm * 128;

  if (tid < 128) sIds[tid] = GATHER ? idsg[z * CAPn + row0 + tid] : (row0 + tid);
  __syncthreads();

  const int lr = lane >> 3;
  const int lc = lane & 7;
  const int srcb = ((lc ^ lr) << 4);
  const unsigned char* Xb = (const unsigned char*)X;
  const unsigned char* Gb = (const unsigned char*)Wg + (size_t)z * N * (K * 2);
  const unsigned char* Ub = (const unsigned char*)Wu + (size_t)z * N * (K * 2);
  const unsigned char* aP[4];
#pragma unroll
  for (int i = 0; i < 4; ++i) {
    int ar = w * 32 + 8 * i + lr;
    aP[i] = Xb + (size_t)sIds[ar] * (K * 2) + srcb;
  }
  const int br0 = bn * 128 + w * 32 + lr;
  const unsigned char* gP0 = Gb + (size_t)br0 * (K * 2) + srcb;
  const unsigned char* uP0 = Ub + (size_t)br0 * (K * 2) + srcb;

  f32x4 accG[4][4], accU[4][4];
#pragma unroll
  for (int m = 0; m < 4; ++m)
#pragma unroll
    for (int n = 0; n < 4; ++n) {
      accG[m][n] = {0.f, 0.f, 0.f, 0.f};
      accU[m][n] = {0.f, 0.f, 0.f, 0.f};
    }

  for (int k0b = 0; k0b < K * 2; k0b += 128) {
    __syncthreads();
#pragma unroll
    for (int i = 0; i < 4; ++i) {
      unsigned ldsoff = (unsigned)(w * 32 + 8 * i) * 128u;
      gload16(aP[i] + k0b, sA + ldsoff);
      gload16(gP0 + (size_t)i * 8 * (K * 2) + k0b, sB1 + ldsoff);
      gload16(uP0 + (size_t)i * 8 * (K * 2) + k0b, sB2 + ldsoff);
    }
    __syncthreads();
#pragma unroll
    for (int ks = 0; ks < 2; ++ks) {
      const int swb = (((ks * 4 + lk) ^ (lrow & 7)) << 4);
      bf16x8 av[4], gv[4], uv[4];
#pragma unroll
      for (int m = 0; m < 4; ++m)
        av[m] = *(const bf16x8*)(sA + (wm * 64 + m * 16 + lrow) * 128 + swb);
#pragma unroll
      for (int n = 0; n < 4; ++n) {
        gv[n] = *(const bf16x8*)(sB1 + (wn * 64 + n * 16 + lrow) * 128 + swb);
        uv[n] = *(const bf16x8*)(sB2 + (wn * 64 + n * 16 + lrow) * 128 + swb);
      }
#pragma unroll
      for (int m = 0; m < 4; ++m)
#pragma unroll
        for (int n = 0; n < 4; ++n) {
          accG[m][n] = __builtin_amdgcn_mfma_f32_16x16x32_bf16(av[m], gv[n], accG[m][n], 0, 0, 0);
          accU[m][n] = __builtin_amdgcn_mfma_f32_16x16x32_bf16(av[m], uv[n], accU[m][n], 0, 0, 0);
        }
    }
  }
#pragma unroll
  for (int n = 0; n < 4; ++n) {
    int col = bn * 128 + wn * 64 + n * 16 + lrow;
    float bg = biasg ? biasg[(size_t)z * N + col] : 0.f;
    float bu = biasu ? biasu[(size_t)z * N + col] : 0.f;
#pragma unroll
    for (int m = 0; m < 4; ++m) {
#pragma unroll
      for (int j = 0; j < 4; ++j) {
        float g = accG[m][n][j] + bg;
        float u = accU[m][n][j] + bu;
        float h = g / (1.f + __expf(-g)) * u;
        int row = row0 + wm * 64 + m * 16 + lk * 4 + j;
        H[(size_t)z * Mz * N + (size_t)row * N + col] = f2bf(h);
      }
    }
  }
}

// down (shared): Out = A@W^T dense store, BM=128 BN=128, K = SHn
template <int K, bool SCATTER>
__global__ __launch_bounds__(256, 2) void kdown_bf(
    const unsigned short* __restrict__ Hin, const unsigned short* __restrict__ W,
    const float* __restrict__ bias, const int* __restrict__ idsg,
    const float* __restrict__ scg, float* __restrict__ Out, int Mz, int MB, int NB,
    int gemmN, int convP,
    const float* __restrict__ cS1, unsigned short* __restrict__ cD1, int cn1) {
  constexpr int N = Dn;
  __shared__ alignas(16) unsigned char sA[16384];
  __shared__ alignas(16) unsigned char sB[16384];
  __shared__ int sIds[128];
  __shared__ float sSc[128];
  const int tid = threadIdx.x;
  const int bid = blockIdx.x;
  if (convP && (bid % convP) == convP - 1) {
    conv4(bid / convP, gridDim.x - gemmN, tid, cS1, cD1, cn1);
    return;
  }
  const int gbid = convP ? (bid - bid / convP) : bid;
  const int cpx = gemmN >> 3;
  const int swz = (gbid & 7) * cpx + (gbid >> 3);
  const int bm = swz % MB;
  const int bn = (swz / MB) % NB;
  const int z  = swz / (MB * NB);
  const int lane = tid & 63, w = tid >> 6;
  const int wm = w >> 1, wn = w & 1;
  const int lrow = lane & 15, lk = lane >> 4;
  const int row0 = bm * 128;

  if (SCATTER && tid < 128) {
    sIds[tid] = idsg[z * CAPn + row0 + tid];
    sSc[tid] = scg[z * CAPn + row0 + tid];
  }
  __syncthreads();

  const int lr = lane >> 3;
  const int lc = lane & 7;
  const int srcb = ((lc ^ lr) << 4);
  const unsigned char* Ab = (const unsigned char*)Hin + (size_t)z * Mz * (K * 2);
  const unsigned char* Wb = (const unsigned char*)W + (size_t)z * N * (K * 2);
  const int ar0 = row0 + w * 32 + lr;
  const int br0 = bn * 128 + w * 32 + lr;
  const unsigned char* aP0 = Ab + (size_t)ar0 * (K * 2) + srcb;
  const unsigned char* bP0 = Wb + (size_t)br0 * (K * 2) + srcb;

  f32x4 acc[4][4];
#pragma unroll
  for (int m = 0; m < 4; ++m)
#pragma unroll
    for (int n = 0; n < 4; ++n) acc[m][n] = {0.f, 0.f, 0.f, 0.f};

  for (int k0b = 0; k0b < K * 2; k0b += 128) {
    __syncthreads();
#pragma unroll
    for (int i = 0; i < 4; ++i) {
      unsigned ldsoff = (unsigned)(w * 32 + 8 * i) * 128u;
      gload16(aP0 + (size_t)i * 8 * (K * 2) + k0b, sA + ldsoff);
      gload16(bP0 + (size_t)i * 8 * (K * 2) + k0b, sB + ldsoff);
    }
    __syncthreads();
#pragma unroll
    for (int ks = 0; ks < 2; ++ks) {
      const int swb = (((ks * 4 + lk) ^ (lrow & 7)) << 4);
      bf16x8 av[4], bv[4];
#pragma unroll
      for (int m = 0; m < 4; ++m)
        av[m] = *(const bf16x8*)(sA + (wm * 64 + m * 16 + lrow) * 128 + swb);
#pragma unroll
      for (int n = 0; n < 4; ++n)
        bv[n] = *(const bf16x8*)(sB + (wn * 64 + n * 16 + lrow) * 128 + swb);
#pragma unroll
      for (int m = 0; m < 4; ++m)
#pragma unroll
        for (int n = 0; n < 4; ++n)
          acc[m][n] = __builtin_amdgcn_mfma_f32_16x16x32_bf16(av[m], bv[n], acc[m][n], 0, 0, 0);
    }
  }
#pragma unroll
  for (int n = 0; n < 4; ++n) {
    int col = bn * 128 + wn * 64 + n * 16 + lrow;
    float bvv = bias ? bias[(size_t)z * N + col] : 0.f;
#pragma unroll
    for (int m = 0; m < 4; ++m) {
#pragma unroll
      for (int j = 0; j < 4; ++j) {
        int rl = wm * 64 + m * 16 + lk * 4 + j;
        float v = acc[m][n][j] + bvv;
        if (SCATTER) {
          atomicAdd(Out + (size_t)sIds[rl] * Dn + col, sSc[rl] * v);
        } else {
          Out[(size_t)(row0 + rl) * Dn + col] = v;
        }
      }
    }
  }
}

// expert down, fat N-tile: BM=128, BN=256, K=Fn, scatter atomicAdd*score
__global__ __launch_bounds__(256, 2) void kdown256(
    const unsigned short* __restrict__ Hin, const unsigned short* __restrict__ W,
    const float* __restrict__ bias, const int* __restrict__ idsg,
    const float* __restrict__ scg, float* __restrict__ Out) {
  constexpr int K = Fn;
  constexpr int N = Dn;
  constexpr int MB = CAPn / 128;   // 8
  constexpr int NB = Dn / 256;     // 4
  __shared__ alignas(16) unsigned char sA[16384];
  __shared__ alignas(16) unsigned char sB[32768];
  __shared__ int sIds[128];
  __shared__ float sSc[128];
  const int tid = threadIdx.x;
  const int bid = blockIdx.x;
  const int cpx = gridDim.x >> 3;
  const int swz = (bid & 7) * cpx + (bid >> 3);
  const int bm = swz % MB;
  const int bn = (swz / MB) % NB;
  const int z  = swz / (MB * NB);
  const int lane = tid & 63, w = tid >> 6;
  const int wm = w >> 1, wn = w & 1;
  const int lrow = lane & 15, lk = lane >> 4;
  const int row0 = bm * 128;

  if (tid < 128) {
    sIds[tid] = idsg[z * CAPn + row0 + tid];
    sSc[tid] = scg[z * CAPn + row0 + tid];
  }
  __syncthreads();

  const int lr = lane >> 3;
  const int lc = lane & 7;
  const int srcb = ((lc ^ lr) << 4);
  const unsigned char* Ab = (const unsigned char*)Hin + (size_t)z * CAPn * (K * 2);
  const unsigned char* Wb = (const unsigned char*)W + (size_t)z * N * (K * 2);
  const int ar0 = row0 + w * 32 + lr;
  const int br0 = bn * 256 + w * 64 + lr;
  const unsigned char* aP0 = Ab + (size_t)ar0 * (K * 2) + srcb;
  const unsigned char* bP0 = Wb + (size_t)br0 * (K * 2) + srcb;

  f32x4 acc[4][8];
#pragma unroll
  for (int m = 0; m < 4; ++m)
#pragma unroll
    for (int n = 0; n < 8; ++n) acc[m][n] = {0.f, 0.f, 0.f, 0.f};

  for (int k0b = 0; k0b < K * 2; k0b += 128) {
    __syncthreads();
#pragma unroll
    for (int i = 0; i < 4; ++i)
      gload16(aP0 + (size_t)i * 8 * (K * 2) + k0b,
              sA + (unsigned)(w * 32 + 8 * i) * 128u);
#pragma unroll
    for (int i = 0; i < 8; ++i)
      gload16(bP0 + (size_t)i * 8 * (K * 2) + k0b,
              sB + (unsigned)(w * 64 + 8 * i) * 128u);
    __syncthreads();
#pragma unroll
    for (int ks = 0; ks < 2; ++ks) {
      const int swb = (((ks * 4 + lk) ^ (lrow & 7)) << 4);
      bf16x8 av[4], bv[8];
#pragma unroll
      for (int m = 0; m < 4; ++m)
        av[m] = *(const bf16x8*)(sA + (wm * 64 + m * 16 + lrow) * 128 + swb);
#pragma unroll
      for (int n = 0; n < 8; ++n)
        bv[n] = *(const bf16x8*)(sB + (wn * 128 + n * 16 + lrow) * 128 + swb);
#pragma unroll
      for (int m = 0; m < 4; ++m)
#pragma unroll
        for (int n = 0; n < 8; ++n)
          acc[m][n] = __builtin_amdgcn_mfma_f32_16x16x32_bf16(av[m], bv[n], acc[m][n], 0, 0, 0);
    }
  }
#pragma unroll
  for (int n = 0; n < 8; ++n) {
    int col = bn * 256 + wn * 128 + n * 16 + lrow;
    float bvv = bias[(size_t)z * N + col];
#pragma unroll
    for (int m = 0; m < 4; ++m) {
#pragma unroll
      for (int j = 0; j < 4; ++j) {
        int rl = wm * 64 + m * 16 + lk * 4 + j;
        atomicAdd(Out + (size_t)sIds[rl] * Dn + col, sSc[rl] * (acc[m][n][j] + bvv));
      }
    }
  }
}

extern "C" void kernel_launch(void* const* d_in, const int* in_sizes, int n_in,
                              void* d_out, int out_size, void* d_ws, size_t ws_size,
                              hipStream_t stream) {
  const float* x      = (const float*)d_in[0];
  const float* gate_w = (const float*)d_in[1];
  const float* up_w   = (const float*)d_in[2];
  const float* up_b   = (const float*)d_in[3];
  const float* gw     = (const float*)d_in[4];
  const float* gb     = (const float*)d_in[5];
  const float* down_w = (const float*)d_in[6];
  const float* down_b = (const float*)d_in[7];
  const float* shg    = (const float*)d_in[8];
  const float* shu    = (const float*)d_in[9];
  const float* shd    = (const float*)d_in[10];
  float* out = (float*)d_out;

  const size_t H_BYTES  = (size_t)En * CAPn * Fn * 2;   // 134 MiB
  const size_t XB_BYTES = (size_t)Tn * Dn * 2;          // 16 MiB
  const size_t WE_BYTES = (size_t)En * Fn * Dn * 2;     // 128 MiB each
  const size_t SH_BYTES = (size_t)SHn * Dn * 2;         // 4 MiB each
  const size_t SC_BYTES = (size_t)En * Tn * 4;
  const size_t ID_BYTES = (size_t)En * CAPn * 4;
  const size_t need = H_BYTES + XB_BYTES + 3 * WE_BYTES + 3 * SH_BYTES +
                      SC_BYTES + 2 * ID_BYTES;
  if (ws_size < need) return;

  char* p = (char*)d_ws;
  unsigned short* H    = (unsigned short*)p; p += H_BYTES;
  unsigned short* xb   = (unsigned short*)p; p += XB_BYTES;
  unsigned short* upb  = (unsigned short*)p; p += WE_BYTES;
  unsigned short* gwb  = (unsigned short*)p; p += WE_BYTES;
  unsigned short* dwb  = (unsigned short*)p; p += WE_BYTES;
  unsigned short* shgb = (unsigned short*)p; p += SH_BYTES;
  unsigned short* shub = (unsigned short*)p; p += SH_BYTES;
  unsigned short* shdb = (unsigned short*)p; p += SH_BYTES;
  float* scores = (float*)p; p += SC_BYTES;
  int* ids      = (int*)p;  p += ID_BYTES;
  float* osc    = (float*)p;

  constexpr int NWE8 = En * Fn * Dn / 8;   // bf16x8 chunks per expert-weight tensor

  // K1: scores (4 tok/block) + x->bf16 + shared-weight converts
  kscores_cvt<<<Tn / 4 + 256, 256, 0, stream>>>(x, gate_w, scores, xb,
                                                shg, shgb, shu, shub, shd, shdb);

  // K3: 16 select blocks + shared GLU (1024 GEMM) + up_w conv striped 1:1
  kglu_bf<false><<<16 + 1024 + 1024, 256, 0, stream>>>(
      xb, nullptr, shgb, shub, nullptr, nullptr, H, SHn, Tn, Tn / 128, SHn / 128,
      1024, 2, up_w, upb, NWE8,
      En, scores, ids, osc);

  // K4: shared down (512 GEMM) + gw conv striped 1:1 (P=2, 512 conv)
  kdown_bf<SHn, false><<<512 + 512, 256, 0, stream>>>(
      H, shdb, nullptr, nullptr, nullptr, out, Tn, Tn / 128, Dn / 128,
      512, 2, gw, gwb, NWE8);

  // K5: expert GLU (4096 GEMM) + down_w conv striped 4:1 (P=5, 1024 conv)
  kglu_bf<true><<<4096 + 1024, 256, 0, stream>>>(
      xb, ids, gwb, upb, gb, up_b, H, Fn, CAPn, CAPn / 128, Fn / 128,
      4096, 5, down_w, dwb, NWE8,
      0, nullptr, nullptr, nullptr);

  // K6: expert down, fat-N tile (512 blocks = 2/CU, one slot-round)
  kdown256<<<(CAPn / 128) * (Dn / 256) * En, 256, 0, stream>>>(
      H, dwb, down_b, ids, osc, out);
}

// Round 18
// 844.338 us; speedup vs baseline: 1.1531x; 1.0522x over previous
//
#include <hip/hip_runtime.h>
#include <hip/hip_bf16.h>

#define Tn 8192
#define Dn 1024
#define Fn 4096
#define SHn 2048
#define En 16
#define CAPn 1024

typedef __bf16 bf16_t;
typedef bf16_t bf16x8 __attribute__((ext_vector_type(8)));
typedef float f32x4 __attribute__((ext_vector_type(4)));

__device__ __forceinline__ unsigned short f2bf(float f) {
  unsigned int u = __builtin_bit_cast(unsigned int, f);
  u += 0x7FFFu + ((u >> 16) & 1u);
  return (unsigned short)(u >> 16);
}
__device__ __forceinline__ unsigned int pack2(float a, float b) {
  return (unsigned int)f2bf(a) | ((unsigned int)f2bf(b) << 16);
}

__device__ __forceinline__ void gload16(const void* g, void* l) {
  __builtin_amdgcn_global_load_lds(
      (const __attribute__((address_space(1))) unsigned int*)g,
      (__attribute__((address_space(3))) unsigned int*)l, 16, 0, 0);
}

// simple grid-stride fp32->bf16 over up to two tensors (small shared tensors)
__device__ __forceinline__ void conv_blocks(int cb, int ncb, int tid,
                                            const float* s1, unsigned short* d1, int n1,
                                            const float* s2, unsigned short* d2, int n2) {
  const int tot = n1 + n2;
  for (int i = cb * 256 + tid; i < tot; i += ncb * 256) {
    const float4* sv; uint4* dv; int j;
    if (i < n1) { j = i; sv = (const float4*)s1; dv = (uint4*)d1; }
    else        { j = i - n1; sv = (const float4*)s2; dv = (uint4*)d2; }
    float4 a = sv[2 * j], b = sv[2 * j + 1];
    dv[j] = uint4{ pack2(a.x, a.y), pack2(a.z, a.w), pack2(b.x, b.y), pack2(b.z, b.w) };
  }
}

// 4-way-ILP grid-stride fp32->bf16 (single tensor) for fused conv blocks
__device__ __forceinline__ void conv4(int cb, int ncb, int tid,
                                      const float* __restrict__ s,
                                      unsigned short* __restrict__ d, int n8) {
  const int step = ncb * 256;
  const float4* sv = (const float4*)s;
  uint4* dv = (uint4*)d;
  for (int i = cb * 256 + tid; i < n8; i += 4 * step) {
    const int i1 = i + step, i2 = i + 2 * step, i3 = i + 3 * step;
    const bool v1 = i1 < n8, v2 = i2 < n8, v3 = i3 < n8;
    float4 a0 = sv[2 * i], b0 = sv[2 * i + 1];
    float4 a1{}, b1{}, a2{}, b2{}, a3{}, b3{};
    if (v1) { a1 = sv[2 * i1]; b1 = sv[2 * i1 + 1]; }
    if (v2) { a2 = sv[2 * i2]; b2 = sv[2 * i2 + 1]; }
    if (v3) { a3 = sv[2 * i3]; b3 = sv[2 * i3 + 1]; }
    dv[i] = uint4{ pack2(a0.x, a0.y), pack2(a0.z, a0.w), pack2(b0.x, b0.y), pack2(b0.z, b0.w) };
    if (v1) dv[i1] = uint4{ pack2(a1.x, a1.y), pack2(a1.z, a1.w), pack2(b1.x, b1.y), pack2(b1.z, b1.w) };
    if (v2) dv[i2] = uint4{ pack2(a2.x, a2.y), pack2(a2.z, a2.w), pack2(b2.x, b2.y), pack2(b2.z, b2.w) };
    if (v3) dv[i3] = uint4{ pack2(a3.x, a3.y), pack2(a3.z, a3.w), pack2(b3.x, b3.y), pack2(b3.z, b3.w) };
  }
}

// per-expert top-CAP radix select over scores[e][*] using a 49664B smem block
__device__ __forceinline__ void do_select(unsigned char* smem, int tid, int e,
                                          const float* __restrict__ scores,
                                          int* __restrict__ ids,
                                          float* __restrict__ oscore) {
  unsigned int* keys = (unsigned int*)smem;                 // 32 KB
  unsigned int* hist = (unsigned int*)(smem + 32768);       // 1 KB
  int* eqlist = (int*)(smem + 33792);                       // 4 KB
  unsigned int* st = (unsigned int*)(smem + 37888);         // prefix,k,cnt,eq
  const float* row = scores + (size_t)e * Tn;
  for (int i = 0; i < Tn / 256; ++i)
    keys[tid + i * 256] = __float_as_uint(row[tid + i * 256]);
  if (tid == 0) { st[0] = 0u; st[1] = CAPn; }
  __syncthreads();
  for (int shift = 24; shift >= 0; shift -= 8) {
    hist[tid] = 0u;
    __syncthreads();
    unsigned int prefix = st[0];
    unsigned int mask = (shift == 24) ? 0u : (0xFFFFFFFFu << (shift + 8));
    for (int i = 0; i < Tn / 256; ++i) {
      unsigned int kk = keys[tid + i * 256];
      if ((kk & mask) == prefix) atomicAdd(&hist[(kk >> shift) & 255], 1u);
    }
    __syncthreads();
    if (tid == 0) {
      unsigned int k = st[1], c = 0; int b;
      for (b = 255; b >= 0; --b) { c += hist[b]; if (c >= k) break; }
      st[1] = k - (c - hist[b]);
      st[0] = prefix | ((unsigned int)b << shift);
    }
    __syncthreads();
  }
  const unsigned int thr = st[0];
  if (tid == 0) { st[2] = 0u; st[3] = 0u; }
  __syncthreads();
  const int base = e * CAPn;
  for (int i = 0; i < Tn / 256; ++i) {
    int t = tid + i * 256;
    unsigned int kk = keys[t];
    if (kk > thr) {
      unsigned int p = atomicAdd(&st[2], 1u);
      ids[base + p] = t;
      oscore[base + p] = __uint_as_float(kk);
    } else if (kk == thr) {
      unsigned int p = atomicAdd(&st[3], 1u);
      if (p < 1024u) eqlist[p] = t;
    }
  }
  __syncthreads();
  if (tid == 0) {
    int need = CAPn - (int)st[2];
    int m = (int)st[3]; if (m > 1024) m = 1024;
    for (int j = 0; j < need; ++j) {
      int best = 1 << 30, bi = 0;
      for (int i2 = 0; i2 < m; ++i2)
        if (eqlist[i2] < best) { best = eqlist[i2]; bi = i2; }
      eqlist[bi] = 1 << 30;
      ids[base + (int)st[2] + j] = best;
      oscore[base + (int)st[2] + j] = __uint_as_float(thr);
    }
  }
}

// ---------------- gate scores (4 tokens/block) + x->bf16 + shared-weight converts ----------------
__global__ __launch_bounds__(256) void kscores_cvt(
    const float* __restrict__ x, const float* __restrict__ gw,
    float* __restrict__ sc, unsigned short* __restrict__ xb,
    const float* __restrict__ shg, unsigned short* __restrict__ shgb,
    const float* __restrict__ shu, unsigned short* __restrict__ shub,
    const float* __restrict__ shd, unsigned short* __restrict__ shdb) {
  __shared__ float sx[Dn];
  const int tid = threadIdx.x;
  constexpr int NSB = Tn / 4;   // 2048 score blocks
  if (blockIdx.x >= NSB) {
    const int cb = blockIdx.x - NSB, ncb = gridDim.x - NSB;
    constexpr int nsh = SHn * Dn / 8;
    conv_blocks(cb, ncb, tid, shg, shgb, nsh, shu, shub, nsh);
    conv_blocks(cb, ncb, tid, shd, shdb, nsh, nullptr, nullptr, 0);
    return;
  }
  const int e = tid >> 4, kl = tid & 15;
  const float4* w = (const float4*)(gw + e * Dn);
#pragma unroll 1
  for (int t4 = 0; t4 < 4; ++t4) {
    const int tok = blockIdx.x * 4 + t4;
    float4 v = ((const float4*)(x + (size_t)tok * Dn))[tid];
    ((float4*)sx)[tid] = v;
    ((uint2*)(xb + (size_t)tok * Dn))[tid] = uint2{ pack2(v.x, v.y), pack2(v.z, v.w) };
    __syncthreads();
    const float4* xv = (const float4*)sx;
    float acc = 0.f;
#pragma unroll
    for (int j = 0; j < 16; ++j) {
      float4 a = w[kl + 16 * j], b = xv[kl + 16 * j];
      acc += a.x * b.x + a.y * b.y + a.z * b.z + a.w * b.w;
    }
#pragma unroll
    for (int off = 8; off; off >>= 1) acc += __shfl_xor(acc, off, 64);
    if (kl == 0) sc[(size_t)e * Tn + tok] = 1.f / (1.f + expf(-acc));
    __syncthreads();
  }
}

// =====================================================================
// Proven round-2 GEMMs (2-phase, 128x128, 16x16x32 MFMA, (256,2)) with
// SELECT blocks at the grid front and STRIPED dual-tensor conv blocks.
// =====================================================================

// GLU: H = bf16( silu(A@Wg^T + bg) * (A@Wu^T + bu) ), K = Dn
template <bool GATHER>
__global__ __launch_bounds__(256, 2) void kglu_bf(
    const unsigned short* __restrict__ X, const int* __restrict__ idsg,
    const unsigned short* __restrict__ Wg, const unsigned short* __restrict__ Wu,
    const float* __restrict__ biasg, const float* __restrict__ biasu,
    unsigned short* __restrict__ H, int N, int Mz, int MB, int NB,
    int gemmN, int convP,
    const float* __restrict__ cS1, unsigned short* __restrict__ cD1, int cn1,
    const float* __restrict__ cS2, unsigned short* __restrict__ cD2, int cn2,
    int selN, const float* __restrict__ selSc, int* __restrict__ selIds,
    float* __restrict__ selOsc) {
  constexpr int K = Dn;
  __shared__ alignas(16) unsigned char smem[49664];
  unsigned char* sA  = smem;
  unsigned char* sB1 = smem + 16384;
  unsigned char* sB2 = smem + 32768;
  int* sIds = (int*)(smem + 49152);
  const int tid = threadIdx.x;
  const int bid0 = blockIdx.x;
  if (bid0 < selN) { do_select(smem, tid, bid0, selSc, selIds, selOsc); return; }
  const int bid = bid0 - selN;
  if (convP && (bid % convP) == convP - 1) {
    const int cb = bid / convP, ncb = gridDim.x - selN - gemmN;
    conv4(cb, ncb, tid, cS1, cD1, cn1);
    if (cn2) conv4(cb, ncb, tid, cS2, cD2, cn2);
    return;
  }
  const int gbid = convP ? (bid - bid / convP) : bid;
  const int cpx = gemmN >> 3;
  const int swz = (gbid & 7) * cpx + (gbid >> 3);
  const int bm = swz % MB;
  const int bn = (swz / MB) % NB;
  const int z  = swz / (MB * NB);
  const int lane = tid & 63, w = tid >> 6;
  const int wm = w >> 1, wn = w & 1;
  const int lrow = lane & 15, lk = lane >> 4;
  const int row0 = bm * 128;

  if (tid < 128) sIds[tid] = GATHER ? idsg[z * CAPn + row0 + tid] : (row0 + tid);
  __syncthreads();

  const int lr = lane >> 3;
  const int lc = lane & 7;
  const int srcb = ((lc ^ lr) << 4);
  const unsigned char* Xb = (const unsigned char*)X;
  const unsigned char* Gb = (const unsigned char*)Wg + (size_t)z * N * (K * 2);
  const unsigned char* Ub = (const unsigned char*)Wu + (size_t)z * N * (K * 2);
  const unsigned char* aP[4];
#pragma unroll
  for (int i = 0; i < 4; ++i) {
    int ar = w * 32 + 8 * i + lr;
    aP[i] = Xb + (size_t)sIds[ar] * (K * 2) + srcb;
  }
  const int br0 = bn * 128 + w * 32 + lr;
  const unsigned char* gP0 = Gb + (size_t)br0 * (K * 2) + srcb;
  const unsigned char* uP0 = Ub + (size_t)br0 * (K * 2) + srcb;

  f32x4 accG[4][4], accU[4][4];
#pragma unroll
  for (int m = 0; m < 4; ++m)
#pragma unroll
    for (int n = 0; n < 4; ++n) {
      accG[m][n] = {0.f, 0.f, 0.f, 0.f};
      accU[m][n] = {0.f, 0.f, 0.f, 0.f};
    }

  for (int k0b = 0; k0b < K * 2; k0b += 128) {
    __syncthreads();
#pragma unroll
    for (int i = 0; i < 4; ++i) {
      unsigned ldsoff = (unsigned)(w * 32 + 8 * i) * 128u;
      gload16(aP[i] + k0b, sA + ldsoff);
      gload16(gP0 + (size_t)i * 8 * (K * 2) + k0b, sB1 + ldsoff);
      gload16(uP0 + (size_t)i * 8 * (K * 2) + k0b, sB2 + ldsoff);
    }
    __syncthreads();
#pragma unroll
    for (int ks = 0; ks < 2; ++ks) {
      const int swb = (((ks * 4 + lk) ^ (lrow & 7)) << 4);
      bf16x8 av[4], gv[4], uv[4];
#pragma unroll
      for (int m = 0; m < 4; ++m)
        av[m] = *(const bf16x8*)(sA + (wm * 64 + m * 16 + lrow) * 128 + swb);
#pragma unroll
      for (int n = 0; n < 4; ++n) {
        gv[n] = *(const bf16x8*)(sB1 + (wn * 64 + n * 16 + lrow) * 128 + swb);
        uv[n] = *(const bf16x8*)(sB2 + (wn * 64 + n * 16 + lrow) * 128 + swb);
      }
#pragma unroll
      for (int m = 0; m < 4; ++m)
#pragma unroll
        for (int n = 0; n < 4; ++n) {
          accG[m][n] = __builtin_amdgcn_mfma_f32_16x16x32_bf16(av[m], gv[n], accG[m][n], 0, 0, 0);
          accU[m][n] = __builtin_amdgcn_mfma_f32_16x16x32_bf16(av[m], uv[n], accU[m][n], 0, 0, 0);
        }
    }
  }
#pragma unroll
  for (int n = 0; n < 4; ++n) {
    int col = bn * 128 + wn * 64 + n * 16 + lrow;
    float bg = biasg ? biasg[(size_t)z * N + col] : 0.f;
    float bu = biasu ? biasu[(size_t)z * N + col] : 0.f;
#pragma unroll
    for (int m = 0; m < 4; ++m) {
#pragma unroll
      for (int j = 0; j < 4; ++j) {
        float g = accG[m][n][j] + bg;
        float u = accU[m][n][j] + bu;
        float h = g / (1.f + __expf(-g)) * u;
        int row = row0 + wm * 64 + m * 16 + lk * 4 + j;
        H[(size_t)z * Mz * N + (size_t)row * N + col] = f2bf(h);
      }
    }
  }
}

// down (shared): Out = A@W^T dense store, BM=128 BN=128, K = SHn
template <int K, bool SCATTER>
__global__ __launch_bounds__(256, 2) void kdown_bf(
    const unsigned short* __restrict__ Hin, const unsigned short* __restrict__ W,
    const float* __restrict__ bias, const int* __restrict__ idsg,
    const float* __restrict__ scg, float* __restrict__ Out, int Mz, int MB, int NB,
    int gemmN, int convP,
    const float* __restrict__ cS1, unsigned short* __restrict__ cD1, int cn1) {
  constexpr int N = Dn;
  __shared__ alignas(16) unsigned char sA[16384];
  __shared__ alignas(16) unsigned char sB[16384];
  __shared__ int sIds[128];
  __shared__ float sSc[128];
  const int tid = threadIdx.x;
  const int bid = blockIdx.x;
  if (convP && (bid % convP) == convP - 1) {
    conv4(bid / convP, gridDim.x - gemmN, tid, cS1, cD1, cn1);
    return;
  }
  const int gbid = convP ? (bid - bid / convP) : bid;
  const int cpx = gemmN >> 3;
  const int swz = (gbid & 7) * cpx + (gbid >> 3);
  const int bm = swz % MB;
  const int bn = (swz / MB) % NB;
  const int z  = swz / (MB * NB);
  const int lane = tid & 63, w = tid >> 6;
  const int wm = w >> 1, wn = w & 1;
  const int lrow = lane & 15, lk = lane >> 4;
  const int row0 = bm * 128;

  if (SCATTER && tid < 128) {
    sIds[tid] = idsg[z * CAPn + row0 + tid];
    sSc[tid] = scg[z * CAPn + row0 + tid];
  }
  __syncthreads();

  const int lr = lane >> 3;
  const int lc = lane & 7;
  const int srcb = ((lc ^ lr) << 4);
  const unsigned char* Ab = (const unsigned char*)Hin + (size_t)z * Mz * (K * 2);
  const unsigned char* Wb = (const unsigned char*)W + (size_t)z * N * (K * 2);
  const int ar0 = row0 + w * 32 + lr;
  const int br0 = bn * 128 + w * 32 + lr;
  const unsigned char* aP0 = Ab + (size_t)ar0 * (K * 2) + srcb;
  const unsigned char* bP0 = Wb + (size_t)br0 * (K * 2) + srcb;

  f32x4 acc[4][4];
#pragma unroll
  for (int m = 0; m < 4; ++m)
#pragma unroll
    for (int n = 0; n < 4; ++n) acc[m][n] = {0.f, 0.f, 0.f, 0.f};

  for (int k0b = 0; k0b < K * 2; k0b += 128) {
    __syncthreads();
#pragma unroll
    for (int i = 0; i < 4; ++i) {
      unsigned ldsoff = (unsigned)(w * 32 + 8 * i) * 128u;
      gload16(aP0 + (size_t)i * 8 * (K * 2) + k0b, sA + ldsoff);
      gload16(bP0 + (size_t)i * 8 * (K * 2) + k0b, sB + ldsoff);
    }
    __syncthreads();
#pragma unroll
    for (int ks = 0; ks < 2; ++ks) {
      const int swb = (((ks * 4 + lk) ^ (lrow & 7)) << 4);
      bf16x8 av[4], bv[4];
#pragma unroll
      for (int m = 0; m < 4; ++m)
        av[m] = *(const bf16x8*)(sA + (wm * 64 + m * 16 + lrow) * 128 + swb);
#pragma unroll
      for (int n = 0; n < 4; ++n)
        bv[n] = *(const bf16x8*)(sB + (wn * 64 + n * 16 + lrow) * 128 + swb);
#pragma unroll
      for (int m = 0; m < 4; ++m)
#pragma unroll
        for (int n = 0; n < 4; ++n)
          acc[m][n] = __builtin_amdgcn_mfma_f32_16x16x32_bf16(av[m], bv[n], acc[m][n], 0, 0, 0);
    }
  }
#pragma unroll
  for (int n = 0; n < 4; ++n) {
    int col = bn * 128 + wn * 64 + n * 16 + lrow;
    float bvv = bias ? bias[(size_t)z * N + col] : 0.f;
#pragma unroll
    for (int m = 0; m < 4; ++m) {
#pragma unroll
      for (int j = 0; j < 4; ++j) {
        int rl = wm * 64 + m * 16 + lk * 4 + j;
        float v = acc[m][n][j] + bvv;
        if (SCATTER) {
          atomicAdd(Out + (size_t)sIds[rl] * Dn + col, sSc[rl] * v);
        } else {
          Out[(size_t)(row0 + rl) * Dn + col] = v;
        }
      }
    }
  }
}

// expert down, fat N-tile: BM=128, BN=256, K=Fn, scatter atomicAdd*score
__global__ __launch_bounds__(256, 2) void kdown256(
    const unsigned short* __restrict__ Hin, const unsigned short* __restrict__ W,
    const float* __restrict__ bias, const int* __restrict__ idsg,
    const float* __restrict__ scg, float* __restrict__ Out) {
  constexpr int K = Fn;
  constexpr int N = Dn;
  constexpr int MB = CAPn / 128;   // 8
  constexpr int NB = Dn / 256;     // 4
  __shared__ alignas(16) unsigned char sA[16384];
  __shared__ alignas(16) unsigned char sB[32768];
  __shared__ int sIds[128];
  __shared__ float sSc[128];
  const int tid = threadIdx.x;
  const int bid = blockIdx.x;
  const int cpx = gridDim.x >> 3;
  const int swz = (bid & 7) * cpx + (bid >> 3);
  const int bm = swz % MB;
  const int bn = (swz / MB) % NB;
  const int z  = swz / (MB * NB);
  const int lane = tid & 63, w = tid >> 6;
  const int wm = w >> 1, wn = w & 1;
  const int lrow = lane & 15, lk = lane >> 4;
  const int row0 = bm * 128;

  if (tid < 128) {
    sIds[tid] = idsg[z * CAPn + row0 + tid];
    sSc[tid] = scg[z * CAPn + row0 + tid];
  }
  __syncthreads();

  const int lr = lane >> 3;
  const int lc = lane & 7;
  const int srcb = ((lc ^ lr) << 4);
  const unsigned char* Ab = (const unsigned char*)Hin + (size_t)z * CAPn * (K * 2);
  const unsigned char* Wb = (const unsigned char*)W + (size_t)z * N * (K * 2);
  const int ar0 = row0 + w * 32 + lr;
  const int br0 = bn * 256 + w * 64 + lr;
  const unsigned char* aP0 = Ab + (size_t)ar0 * (K * 2) + srcb;
  const unsigned char* bP0 = Wb + (size_t)br0 * (K * 2) + srcb;

  f32x4 acc[4][8];
#pragma unroll
  for (int m = 0; m < 4; ++m)
#pragma unroll
    for (int n = 0; n < 8; ++n) acc[m][n] = {0.f, 0.f, 0.f, 0.f};

  for (int k0b = 0; k0b < K * 2; k0b += 128) {
    __syncthreads();
#pragma unroll
    for (int i = 0; i < 4; ++i)
      gload16(aP0 + (size_t)i * 8 * (K * 2) + k0b,
              sA + (unsigned)(w * 32 + 8 * i) * 128u);
#pragma unroll
    for (int i = 0; i < 8; ++i)
      gload16(bP0 + (size_t)i * 8 * (K * 2) + k0b,
              sB + (unsigned)(w * 64 + 8 * i) * 128u);
    __syncthreads();
#pragma unroll
    for (int ks = 0; ks < 2; ++ks) {
      const int swb = (((ks * 4 + lk) ^ (lrow & 7)) << 4);
      bf16x8 av[4], bv[8];
#pragma unroll
      for (int m = 0; m < 4; ++m)
        av[m] = *(const bf16x8*)(sA + (wm * 64 + m * 16 + lrow) * 128 + swb);
#pragma unroll
      for (int n = 0; n < 8; ++n)
        bv[n] = *(const bf16x8*)(sB + (wn * 128 + n * 16 + lrow) * 128 + swb);
#pragma unroll
      for (int m = 0; m < 4; ++m)
#pragma unroll
        for (int n = 0; n < 8; ++n)
          acc[m][n] = __builtin_amdgcn_mfma_f32_16x16x32_bf16(av[m], bv[n], acc[m][n], 0, 0, 0);
    }
  }
#pragma unroll
  for (int n = 0; n < 8; ++n) {
    int col = bn * 256 + wn * 128 + n * 16 + lrow;
    float bvv = bias[(size_t)z * N + col];
#pragma unroll
    for (int m = 0; m < 4; ++m) {
#pragma unroll
      for (int j = 0; j < 4; ++j) {
        int rl = wm * 64 + m * 16 + lk * 4 + j;
        atomicAdd(Out + (size_t)sIds[rl] * Dn + col, sSc[rl] * (acc[m][n][j] + bvv));
      }
    }
  }
}

extern "C" void kernel_launch(void* const* d_in, const int* in_sizes, int n_in,
                              void* d_out, int out_size, void* d_ws, size_t ws_size,
                              hipStream_t stream) {
  const float* x      = (const float*)d_in[0];
  const float* gate_w = (const float*)d_in[1];
  const float* up_w   = (const float*)d_in[2];
  const float* up_b   = (const float*)d_in[3];
  const float* gw     = (const float*)d_in[4];
  const float* gb     = (const float*)d_in[5];
  const float* down_w = (const float*)d_in[6];
  const float* down_b = (const float*)d_in[7];
  const float* shg    = (const float*)d_in[8];
  const float* shu    = (const float*)d_in[9];
  const float* shd    = (const float*)d_in[10];
  float* out = (float*)d_out;

  const size_t H_BYTES  = (size_t)En * CAPn * Fn * 2;   // 134 MiB
  const size_t XB_BYTES = (size_t)Tn * Dn * 2;          // 16 MiB
  const size_t WE_BYTES = (size_t)En * Fn * Dn * 2;     // 128 MiB each
  const size_t SH_BYTES = (size_t)SHn * Dn * 2;         // 4 MiB each
  const size_t SC_BYTES = (size_t)En * Tn * 4;
  const size_t ID_BYTES = (size_t)En * CAPn * 4;
  const size_t need = H_BYTES + XB_BYTES + 3 * WE_BYTES + 3 * SH_BYTES +
                      SC_BYTES + 2 * ID_BYTES;
  if (ws_size < need) return;

  char* p = (char*)d_ws;
  unsigned short* H    = (unsigned short*)p; p += H_BYTES;
  unsigned short* xb   = (unsigned short*)p; p += XB_BYTES;
  unsigned short* upb  = (unsigned short*)p; p += WE_BYTES;
  unsigned short* gwb  = (unsigned short*)p; p += WE_BYTES;
  unsigned short* dwb  = (unsigned short*)p; p += WE_BYTES;
  unsigned short* shgb = (unsigned short*)p; p += SH_BYTES;
  unsigned short* shub = (unsigned short*)p; p += SH_BYTES;
  unsigned short* shdb = (unsigned short*)p; p += SH_BYTES;
  float* scores = (float*)p; p += SC_BYTES;
  int* ids      = (int*)p;  p += ID_BYTES;
  float* osc    = (float*)p;

  constexpr int NWE8 = En * Fn * Dn / 8;   // bf16x8 chunks per expert-weight tensor

  // K1: scores (4 tok/block) + x->bf16 + shared-weight converts
  kscores_cvt<<<Tn / 4 + 256, 256, 0, stream>>>(x, gate_w, scores, xb,
                                                shg, shgb, shu, shub, shd, shdb);

  // K2: 16 select + shared GLU (1024) + up_w AND gw conv striped 1:1 (1024 dual-conv)
  kglu_bf<false><<<16 + 1024 + 1024, 256, 0, stream>>>(
      xb, nullptr, shgb, shub, nullptr, nullptr, H, SHn, Tn, Tn / 128, SHn / 128,
      1024, 2, up_w, upb, NWE8, gw, gwb, NWE8,
      En, scores, ids, osc);

  // K3: shared down (512) + down_w conv striped 1:1 (512 conv)
  kdown_bf<SHn, false><<<512 + 512, 256, 0, stream>>>(
      H, shdb, nullptr, nullptr, nullptr, out, Tn, Tn / 128, Dn / 128,
      512, 2, down_w, dwb, NWE8);

  // K4: expert GLU, clean (4096 blocks)
  kglu_bf<true><<<4096, 256, 0, stream>>>(
      xb, ids, gwb, upb, gb, up_b, H, Fn, CAPn, CAPn / 128, Fn / 128,
      4096, 0, nullptr, nullptr, 0, nullptr, nullptr, 0,
      0, nullptr, nullptr, nullptr);

  // K5: expert down, fat-N tile (512 blocks = 2/CU, one slot-round)
  kdown256<<<(CAPn / 128) * (Dn / 256) * En, 256, 0, stream>>>(
      H, dwb, down_b, ids, osc, out);
}

// Round 19
// 843.271 us; speedup vs baseline: 1.1546x; 1.0013x over previous
//
#include <hip/hip_runtime.h>
#include <hip/hip_bf16.h>

#define Tn 8192
#define Dn 1024
#define Fn 4096
#define SHn 2048
#define En 16
#define CAPn 1024

typedef __bf16 bf16_t;
typedef bf16_t bf16x8 __attribute__((ext_vector_type(8)));
typedef float f32x4 __attribute__((ext_vector_type(4)));

__device__ __forceinline__ unsigned short f2bf(float f) {
  unsigned int u = __builtin_bit_cast(unsigned int, f);
  u += 0x7FFFu + ((u >> 16) & 1u);
  return (unsigned short)(u >> 16);
}
__device__ __forceinline__ unsigned int pack2(float a, float b) {
  return (unsigned int)f2bf(a) | ((unsigned int)f2bf(b) << 16);
}

__device__ __forceinline__ void gload16(const void* g, void* l) {
  __builtin_amdgcn_global_load_lds(
      (const __attribute__((address_space(1))) unsigned int*)g,
      (__attribute__((address_space(3))) unsigned int*)l, 16, 0, 0);
}

// simple grid-stride fp32->bf16 over up to two tensors (small shared tensors)
__device__ __forceinline__ void conv_blocks(int cb, int ncb, int tid,
                                            const float* s1, unsigned short* d1, int n1,
                                            const float* s2, unsigned short* d2, int n2) {
  const int tot = n1 + n2;
  for (int i = cb * 256 + tid; i < tot; i += ncb * 256) {
    const float4* sv; uint4* dv; int j;
    if (i < n1) { j = i; sv = (const float4*)s1; dv = (uint4*)d1; }
    else        { j = i - n1; sv = (const float4*)s2; dv = (uint4*)d2; }
    float4 a = sv[2 * j], b = sv[2 * j + 1];
    dv[j] = uint4{ pack2(a.x, a.y), pack2(a.z, a.w), pack2(b.x, b.y), pack2(b.z, b.w) };
  }
}

// 4-way-ILP grid-stride fp32->bf16 (single tensor) for fused conv blocks
__device__ __forceinline__ void conv4(int cb, int ncb, int tid,
                                      const float* __restrict__ s,
                                      unsigned short* __restrict__ d, int n8) {
  const int step = ncb * 256;
  const float4* sv = (const float4*)s;
  uint4* dv = (uint4*)d;
  for (int i = cb * 256 + tid; i < n8; i += 4 * step) {
    const int i1 = i + step, i2 = i + 2 * step, i3 = i + 3 * step;
    const bool v1 = i1 < n8, v2 = i2 < n8, v3 = i3 < n8;
    float4 a0 = sv[2 * i], b0 = sv[2 * i + 1];
    float4 a1{}, b1{}, a2{}, b2{}, a3{}, b3{};
    if (v1) { a1 = sv[2 * i1]; b1 = sv[2 * i1 + 1]; }
    if (v2) { a2 = sv[2 * i2]; b2 = sv[2 * i2 + 1]; }
    if (v3) { a3 = sv[2 * i3]; b3 = sv[2 * i3 + 1]; }
    dv[i] = uint4{ pack2(a0.x, a0.y), pack2(a0.z, a0.w), pack2(b0.x, b0.y), pack2(b0.z, b0.w) };
    if (v1) dv[i1] = uint4{ pack2(a1.x, a1.y), pack2(a1.z, a1.w), pack2(b1.x, b1.y), pack2(b1.z, b1.w) };
    if (v2) dv[i2] = uint4{ pack2(a2.x, a2.y), pack2(a2.z, a2.w), pack2(b2.x, b2.y), pack2(b2.z, b2.w) };
    if (v3) dv[i3] = uint4{ pack2(a3.x, a3.y), pack2(a3.z, a3.w), pack2(b3.x, b3.y), pack2(b3.z, b3.w) };
  }
}

// per-expert top-CAP radix select over scores[e][*] using a 49664B smem block
__device__ __forceinline__ void do_select(unsigned char* smem, int tid, int e,
                                          const float* __restrict__ scores,
                                          int* __restrict__ ids,
                                          float* __restrict__ oscore) {
  unsigned int* keys = (unsigned int*)smem;                 // 32 KB
  unsigned int* hist = (unsigned int*)(smem + 32768);       // 1 KB
  int* eqlist = (int*)(smem + 33792);                       // 4 KB
  unsigned int* st = (unsigned int*)(smem + 37888);         // prefix,k,cnt,eq
  const float* row = scores + (size_t)e * Tn;
  for (int i = 0; i < Tn / 256; ++i)
    keys[tid + i * 256] = __float_as_uint(row[tid + i * 256]);
  if (tid == 0) { st[0] = 0u; st[1] = CAPn; }
  __syncthreads();
  for (int shift = 24; shift >= 0; shift -= 8) {
    hist[tid] = 0u;
    __syncthreads();
    unsigned int prefix = st[0];
    unsigned int mask = (shift == 24) ? 0u : (0xFFFFFFFFu << (shift + 8));
    for (int i = 0; i < Tn / 256; ++i) {
      unsigned int kk = keys[tid + i * 256];
      if ((kk & mask) == prefix) atomicAdd(&hist[(kk >> shift) & 255], 1u);
    }
    __syncthreads();
    if (tid == 0) {
      unsigned int k = st[1], c = 0; int b;
      for (b = 255; b >= 0; --b) { c += hist[b]; if (c >= k) break; }
      st[1] = k - (c - hist[b]);
      st[0] = prefix | ((unsigned int)b << shift);
    }
    __syncthreads();
  }
  const unsigned int thr = st[0];
  if (tid == 0) { st[2] = 0u; st[3] = 0u; }
  __syncthreads();
  const int base = e * CAPn;
  for (int i = 0; i < Tn / 256; ++i) {
    int t = tid + i * 256;
    unsigned int kk = keys[t];
    if (kk > thr) {
      unsigned int p = atomicAdd(&st[2], 1u);
      ids[base + p] = t;
      oscore[base + p] = __uint_as_float(kk);
    } else if (kk == thr) {
      unsigned int p = atomicAdd(&st[3], 1u);
      if (p < 1024u) eqlist[p] = t;
    }
  }
  __syncthreads();
  if (tid == 0) {
    int need = CAPn - (int)st[2];
    int m = (int)st[3]; if (m > 1024) m = 1024;
    for (int j = 0; j < need; ++j) {
      int best = 1 << 30, bi = 0;
      for (int i2 = 0; i2 < m; ++i2)
        if (eqlist[i2] < best) { best = eqlist[i2]; bi = i2; }
      eqlist[bi] = 1 << 30;
      ids[base + (int)st[2] + j] = best;
      oscore[base + (int)st[2] + j] = __uint_as_float(thr);
    }
  }
}

// ---------------- gate scores (8 tokens/block) + x->bf16 + shared-weight converts ----------------
__global__ __launch_bounds__(256) void kscores_cvt(
    const float* __restrict__ x, const float* __restrict__ gw,
    float* __restrict__ sc, unsigned short* __restrict__ xb,
    const float* __restrict__ shg, unsigned short* __restrict__ shgb,
    const float* __restrict__ shu, unsigned short* __restrict__ shub,
    const float* __restrict__ shd, unsigned short* __restrict__ shdb) {
  __shared__ float sx[Dn];
  const int tid = threadIdx.x;
  constexpr int NSB = Tn / 8;   // 1024 score blocks
  if (blockIdx.x >= NSB) {
    const int cb = blockIdx.x - NSB, ncb = gridDim.x - NSB;
    constexpr int nsh = SHn * Dn / 8;
    conv_blocks(cb, ncb, tid, shg, shgb, nsh, shu, shub, nsh);
    conv_blocks(cb, ncb, tid, shd, shdb, nsh, nullptr, nullptr, 0);
    return;
  }
  const int e = tid >> 4, kl = tid & 15;
  const float4* w = (const float4*)(gw + e * Dn);
#pragma unroll 1
  for (int t8 = 0; t8 < 8; ++t8) {
    const int tok = blockIdx.x * 8 + t8;
    float4 v = ((const float4*)(x + (size_t)tok * Dn))[tid];
    ((float4*)sx)[tid] = v;
    ((uint2*)(xb + (size_t)tok * Dn))[tid] = uint2{ pack2(v.x, v.y), pack2(v.z, v.w) };
    __syncthreads();
    const float4* xv = (const float4*)sx;
    float acc = 0.f;
#pragma unroll
    for (int j = 0; j < 16; ++j) {
      float4 a = w[kl + 16 * j], b = xv[kl + 16 * j];
      acc += a.x * b.x + a.y * b.y + a.z * b.z + a.w * b.w;
    }
#pragma unroll
    for (int off = 8; off; off >>= 1) acc += __shfl_xor(acc, off, 64);
    if (kl == 0) sc[(size_t)e * Tn + tok] = 1.f / (1.f + expf(-acc));
    __syncthreads();
  }
}

// =====================================================================
// Proven round-2 GEMMs (2-phase, 128x128, 16x16x32 MFMA, (256,2)) with
// SELECT blocks at the grid front and STRIPED dual-tensor conv blocks.
// =====================================================================

// GLU: H = bf16( silu(A@Wg^T + bg) * (A@Wu^T + bu) ), K = Dn
template <bool GATHER>
__global__ __launch_bounds__(256, 2) void kglu_bf(
    const unsigned short* __restrict__ X, const int* __restrict__ idsg,
    const unsigned short* __restrict__ Wg, const unsigned short* __restrict__ Wu,
    const float* __restrict__ biasg, const float* __restrict__ biasu,
    unsigned short* __restrict__ H, int N, int Mz, int MB, int NB,
    int gemmN, int convP,
    const float* __restrict__ cS1, unsigned short* __restrict__ cD1, int cn1,
    const float* __restrict__ cS2, unsigned short* __restrict__ cD2, int cn2,
    int selN, const float* __restrict__ selSc, int* __restrict__ selIds,
    float* __restrict__ selOsc) {
  constexpr int K = Dn;
  __shared__ alignas(16) unsigned char smem[49664];
  unsigned char* sA  = smem;
  unsigned char* sB1 = smem + 16384;
  unsigned char* sB2 = smem + 32768;
  int* sIds = (int*)(smem + 49152);
  const int tid = threadIdx.x;
  const int bid0 = blockIdx.x;
  if (bid0 < selN) { do_select(smem, tid, bid0, selSc, selIds, selOsc); return; }
  const int bid = bid0 - selN;
  if (convP && (bid % convP) == convP - 1) {
    const int cb = bid / convP, ncb = gridDim.x - selN - gemmN;
    conv4(cb, ncb, tid, cS1, cD1, cn1);
    if (cn2) conv4(cb, ncb, tid, cS2, cD2, cn2);
    return;
  }
  const int gbid = convP ? (bid - bid / convP) : bid;
  const int cpx = gemmN >> 3;
  const int swz = (gbid & 7) * cpx + (gbid >> 3);
  const int bm = swz % MB;
  const int bn = (swz / MB) % NB;
  const int z  = swz / (MB * NB);
  const int lane = tid & 63, w = tid >> 6;
  const int wm = w >> 1, wn = w & 1;
  const int lrow = lane & 15, lk = lane >> 4;
  const int row0 = bm * 128;

  if (tid < 128) sIds[tid] = GATHER ? idsg[z * CAPn + row0 + tid] : (row0 + tid);
  __syncthreads();

  const int lr = lane >> 3;
  const int lc = lane & 7;
  const int srcb = ((lc ^ lr) << 4);
  const unsigned char* Xb = (const unsigned char*)X;
  const unsigned char* Gb = (const unsigned char*)Wg + (size_t)z * N * (K * 2);
  const unsigned char* Ub = (const unsigned char*)Wu + (size_t)z * N * (K * 2);
  const unsigned char* aP[4];
#pragma unroll
  for (int i = 0; i < 4; ++i) {
    int ar = w * 32 + 8 * i + lr;
    aP[i] = Xb + (size_t)sIds[ar] * (K * 2) + srcb;
  }
  const int br0 = bn * 128 + w * 32 + lr;
  const unsigned char* gP0 = Gb + (size_t)br0 * (K * 2) + srcb;
  const unsigned char* uP0 = Ub + (size_t)br0 * (K * 2) + srcb;

  f32x4 accG[4][4], accU[4][4];
#pragma unroll
  for (int m = 0; m < 4; ++m)
#pragma unroll
    for (int n = 0; n < 4; ++n) {
      accG[m][n] = {0.f, 0.f, 0.f, 0.f};
      accU[m][n] = {0.f, 0.f, 0.f, 0.f};
    }

  for (int k0b = 0; k0b < K * 2; k0b += 128) {
    __syncthreads();
#pragma unroll
    for (int i = 0; i < 4; ++i) {
      unsigned ldsoff = (unsigned)(w * 32 + 8 * i) * 128u;
      gload16(aP[i] + k0b, sA + ldsoff);
      gload16(gP0 + (size_t)i * 8 * (K * 2) + k0b, sB1 + ldsoff);
      gload16(uP0 + (size_t)i * 8 * (K * 2) + k0b, sB2 + ldsoff);
    }
    __syncthreads();
#pragma unroll
    for (int ks = 0; ks < 2; ++ks) {
      const int swb = (((ks * 4 + lk) ^ (lrow & 7)) << 4);
      bf16x8 av[4], gv[4], uv[4];
#pragma unroll
      for (int m = 0; m < 4; ++m)
        av[m] = *(const bf16x8*)(sA + (wm * 64 + m * 16 + lrow) * 128 + swb);
#pragma unroll
      for (int n = 0; n < 4; ++n) {
        gv[n] = *(const bf16x8*)(sB1 + (wn * 64 + n * 16 + lrow) * 128 + swb);
        uv[n] = *(const bf16x8*)(sB2 + (wn * 64 + n * 16 + lrow) * 128 + swb);
      }
#pragma unroll
      for (int m = 0; m < 4; ++m)
#pragma unroll
        for (int n = 0; n < 4; ++n) {
          accG[m][n] = __builtin_amdgcn_mfma_f32_16x16x32_bf16(av[m], gv[n], accG[m][n], 0, 0, 0);
          accU[m][n] = __builtin_amdgcn_mfma_f32_16x16x32_bf16(av[m], uv[n], accU[m][n], 0, 0, 0);
        }
    }
  }
#pragma unroll
  for (int n = 0; n < 4; ++n) {
    int col = bn * 128 + wn * 64 + n * 16 + lrow;
    float bg = biasg ? biasg[(size_t)z * N + col] : 0.f;
    float bu = biasu ? biasu[(size_t)z * N + col] : 0.f;
#pragma unroll
    for (int m = 0; m < 4; ++m) {
#pragma unroll
      for (int j = 0; j < 4; ++j) {
        float g = accG[m][n][j] + bg;
        float u = accU[m][n][j] + bu;
        float h = g / (1.f + __expf(-g)) * u;
        int row = row0 + wm * 64 + m * 16 + lk * 4 + j;
        H[(size_t)z * Mz * N + (size_t)row * N + col] = f2bf(h);
      }
    }
  }
}

// down (shared): Out = A@W^T dense store, BM=128 BN=128, K = SHn
template <int K, bool SCATTER>
__global__ __launch_bounds__(256, 2) void kdown_bf(
    const unsigned short* __restrict__ Hin, const unsigned short* __restrict__ W,
    const float* __restrict__ bias, const int* __restrict__ idsg,
    const float* __restrict__ scg, float* __restrict__ Out, int Mz, int MB, int NB,
    int gemmN, int convP,
    const float* __restrict__ cS1, unsigned short* __restrict__ cD1, int cn1) {
  constexpr int N = Dn;
  __shared__ alignas(16) unsigned char sA[16384];
  __shared__ alignas(16) unsigned char sB[16384];
  __shared__ int sIds[128];
  __shared__ float sSc[128];
  const int tid = threadIdx.x;
  const int bid = blockIdx.x;
  if (convP && (bid % convP) == convP - 1) {
    conv4(bid / convP, gridDim.x - gemmN, tid, cS1, cD1, cn1);
    return;
  }
  const int gbid = convP ? (bid - bid / convP) : bid;
  const int cpx = gemmN >> 3;
  const int swz = (gbid & 7) * cpx + (gbid >> 3);
  const int bm = swz % MB;
  const int bn = (swz / MB) % NB;
  const int z  = swz / (MB * NB);
  const int lane = tid & 63, w = tid >> 6;
  const int wm = w >> 1, wn = w & 1;
  const int lrow = lane & 15, lk = lane >> 4;
  const int row0 = bm * 128;

  if (SCATTER && tid < 128) {
    sIds[tid] = idsg[z * CAPn + row0 + tid];
    sSc[tid] = scg[z * CAPn + row0 + tid];
  }
  __syncthreads();

  const int lr = lane >> 3;
  const int lc = lane & 7;
  const int srcb = ((lc ^ lr) << 4);
  const unsigned char* Ab = (const unsigned char*)Hin + (size_t)z * Mz * (K * 2);
  const unsigned char* Wb = (const unsigned char*)W + (size_t)z * N * (K * 2);
  const int ar0 = row0 + w * 32 + lr;
  const int br0 = bn * 128 + w * 32 + lr;
  const unsigned char* aP0 = Ab + (size_t)ar0 * (K * 2) + srcb;
  const unsigned char* bP0 = Wb + (size_t)br0 * (K * 2) + srcb;

  f32x4 acc[4][4];
#pragma unroll
  for (int m = 0; m < 4; ++m)
#pragma unroll
    for (int n = 0; n < 4; ++n) acc[m][n] = {0.f, 0.f, 0.f, 0.f};

  for (int k0b = 0; k0b < K * 2; k0b += 128) {
    __syncthreads();
#pragma unroll
    for (int i = 0; i < 4; ++i) {
      unsigned ldsoff = (unsigned)(w * 32 + 8 * i) * 128u;
      gload16(aP0 + (size_t)i * 8 * (K * 2) + k0b, sA + ldsoff);
      gload16(bP0 + (size_t)i * 8 * (K * 2) + k0b, sB + ldsoff);
    }
    __syncthreads();
#pragma unroll
    for (int ks = 0; ks < 2; ++ks) {
      const int swb = (((ks * 4 + lk) ^ (lrow & 7)) << 4);
      bf16x8 av[4], bv[4];
#pragma unroll
      for (int m = 0; m < 4; ++m)
        av[m] = *(const bf16x8*)(sA + (wm * 64 + m * 16 + lrow) * 128 + swb);
#pragma unroll
      for (int n = 0; n < 4; ++n)
        bv[n] = *(const bf16x8*)(sB + (wn * 64 + n * 16 + lrow) * 128 + swb);
#pragma unroll
      for (int m = 0; m < 4; ++m)
#pragma unroll
        for (int n = 0; n < 4; ++n)
          acc[m][n] = __builtin_amdgcn_mfma_f32_16x16x32_bf16(av[m], bv[n], acc[m][n], 0, 0, 0);
    }
  }
#pragma unroll
  for (int n = 0; n < 4; ++n) {
    int col = bn * 128 + wn * 64 + n * 16 + lrow;
    float bvv = bias ? bias[(size_t)z * N + col] : 0.f;
#pragma unroll
    for (int m = 0; m < 4; ++m) {
#pragma unroll
      for (int j = 0; j < 4; ++j) {
        int rl = wm * 64 + m * 16 + lk * 4 + j;
        float v = acc[m][n][j] + bvv;
        if (SCATTER) {
          atomicAdd(Out + (size_t)sIds[rl] * Dn + col, sSc[rl] * v);
        } else {
          Out[(size_t)(row0 + rl) * Dn + col] = v;
        }
      }
    }
  }
}

// expert down, fat N-tile: BM=128, BN=256, K=Fn, scatter atomicAdd*score
__global__ __launch_bounds__(256, 2) void kdown256(
    const unsigned short* __restrict__ Hin, const unsigned short* __restrict__ W,
    const float* __restrict__ bias, const int* __restrict__ idsg,
    const float* __restrict__ scg, float* __restrict__ Out) {
  constexpr int K = Fn;
  constexpr int N = Dn;
  constexpr int MB = CAPn / 128;   // 8
  constexpr int NB = Dn / 256;     // 4
  __shared__ alignas(16) unsigned char sA[16384];
  __shared__ alignas(16) unsigned char sB[32768];
  __shared__ int sIds[128];
  __shared__ float sSc[128];
  const int tid = threadIdx.x;
  const int bid = blockIdx.x;
  const int cpx = gridDim.x >> 3;
  const int swz = (bid & 7) * cpx + (bid >> 3);
  const int bm = swz % MB;
  const int bn = (swz / MB) % NB;
  const int z  = swz / (MB * NB);
  const int lane = tid & 63, w = tid >> 6;
  const int wm = w >> 1, wn = w & 1;
  const int lrow = lane & 15, lk = lane >> 4;
  const int row0 = bm * 128;

  if (tid < 128) {
    sIds[tid] = idsg[z * CAPn + row0 + tid];
    sSc[tid] = scg[z * CAPn + row0 + tid];
  }
  __syncthreads();

  const int lr = lane >> 3;
  const int lc = lane & 7;
  const int srcb = ((lc ^ lr) << 4);
  const unsigned char* Ab = (const unsigned char*)Hin + (size_t)z * CAPn * (K * 2);
  const unsigned char* Wb = (const unsigned char*)W + (size_t)z * N * (K * 2);
  const int ar0 = row0 + w * 32 + lr;
  const int br0 = bn * 256 + w * 64 + lr;
  const unsigned char* aP0 = Ab + (size_t)ar0 * (K * 2) + srcb;
  const unsigned char* bP0 = Wb + (size_t)br0 * (K * 2) + srcb;

  f32x4 acc[4][8];
#pragma unroll
  for (int m = 0; m < 4; ++m)
#pragma unroll
    for (int n = 0; n < 8; ++n) acc[m][n] = {0.f, 0.f, 0.f, 0.f};

  for (int k0b = 0; k0b < K * 2; k0b += 128) {
    __syncthreads();
#pragma unroll
    for (int i = 0; i < 4; ++i)
      gload16(aP0 + (size_t)i * 8 * (K * 2) + k0b,
              sA + (unsigned)(w * 32 + 8 * i) * 128u);
#pragma unroll
    for (int i = 0; i < 8; ++i)
      gload16(bP0 + (size_t)i * 8 * (K * 2) + k0b,
              sB + (unsigned)(w * 64 + 8 * i) * 128u);
    __syncthreads();
#pragma unroll
    for (int ks = 0; ks < 2; ++ks) {
      const int swb = (((ks * 4 + lk) ^ (lrow & 7)) << 4);
      bf16x8 av[4], bv[8];
#pragma unroll
      for (int m = 0; m < 4; ++m)
        av[m] = *(const bf16x8*)(sA + (wm * 64 + m * 16 + lrow) * 128 + swb);
#pragma unroll
      for (int n = 0; n < 8; ++n)
        bv[n] = *(const bf16x8*)(sB + (wn * 128 + n * 16 + lrow) * 128 + swb);
#pragma unroll
      for (int m = 0; m < 4; ++m)
#pragma unroll
        for (int n = 0; n < 8; ++n)
          acc[m][n] = __builtin_amdgcn_mfma_f32_16x16x32_bf16(av[m], bv[n], acc[m][n], 0, 0, 0);
    }
  }
#pragma unroll
  for (int n = 0; n < 8; ++n) {
    int col = bn * 256 + wn * 128 + n * 16 + lrow;
    float bvv = bias[(size_t)z * N + col];
#pragma unroll
    for (int m = 0; m < 4; ++m) {
#pragma unroll
      for (int j = 0; j < 4; ++j) {
        int rl = wm * 64 + m * 16 + lk * 4 + j;
        atomicAdd(Out + (size_t)sIds[rl] * Dn + col, sSc[rl] * (acc[m][n][j] + bvv));
      }
    }
  }
}

extern "C" void kernel_launch(void* const* d_in, const int* in_sizes, int n_in,
                              void* d_out, int out_size, void* d_ws, size_t ws_size,
                              hipStream_t stream) {
  const float* x      = (const float*)d_in[0];
  const float* gate_w = (const float*)d_in[1];
  const float* up_w   = (const float*)d_in[2];
  const float* up_b   = (const float*)d_in[3];
  const float* gw     = (const float*)d_in[4];
  const float* gb     = (const float*)d_in[5];
  const float* down_w = (const float*)d_in[6];
  const float* down_b = (const float*)d_in[7];
  const float* shg    = (const float*)d_in[8];
  const float* shu    = (const float*)d_in[9];
  const float* shd    = (const float*)d_in[10];
  float* out = (float*)d_out;

  const size_t H_BYTES  = (size_t)En * CAPn * Fn * 2;   // 134 MiB
  const size_t XB_BYTES = (size_t)Tn * Dn * 2;          // 16 MiB
  const size_t WE_BYTES = (size_t)En * Fn * Dn * 2;     // 128 MiB each
  const size_t SH_BYTES = (size_t)SHn * Dn * 2;         // 4 MiB each
  const size_t SC_BYTES = (size_t)En * Tn * 4;
  const size_t ID_BYTES = (size_t)En * CAPn * 4;
  const size_t need = H_BYTES + XB_BYTES + 3 * WE_BYTES + 3 * SH_BYTES +
                      SC_BYTES + 2 * ID_BYTES;
  if (ws_size < need) return;

  char* p = (char*)d_ws;
  unsigned short* H    = (unsigned short*)p; p += H_BYTES;
  unsigned short* xb   = (unsigned short*)p; p += XB_BYTES;
  unsigned short* upb  = (unsigned short*)p; p += WE_BYTES;
  unsigned short* gwb  = (unsigned short*)p; p += WE_BYTES;
  unsigned short* dwb  = (unsigned short*)p; p += WE_BYTES;
  unsigned short* shgb = (unsigned short*)p; p += SH_BYTES;
  unsigned short* shub = (unsigned short*)p; p += SH_BYTES;
  unsigned short* shdb = (unsigned short*)p; p += SH_BYTES;
  float* scores = (float*)p; p += SC_BYTES;
  int* ids      = (int*)p;  p += ID_BYTES;
  float* osc    = (float*)p;

  constexpr int NWE8 = En * Fn * Dn / 8;   // bf16x8 chunks per expert-weight tensor

  // K1: scores (8 tok/block) + x->bf16 + shared-weight converts
  kscores_cvt<<<Tn / 8 + 256, 256, 0, stream>>>(x, gate_w, scores, xb,
                                                shg, shgb, shu, shub, shd, shdb);

  // K2: 16 select + shared GLU (1024) + up_w AND gw conv striped 1:1 (1024 dual-conv)
  kglu_bf<false><<<16 + 1024 + 1024, 256, 0, stream>>>(
      xb, nullptr, shgb, shub, nullptr, nullptr, H, SHn, Tn, Tn / 128, SHn / 128,
      1024, 2, up_w, upb, NWE8, gw, gwb, NWE8,
      En, scores, ids, osc);

  // K3: shared down (512) + down_w conv striped 1:1 (512 conv)
  kdown_bf<SHn, false><<<512 + 512, 256, 0, stream>>>(
      H, shdb, nullptr, nullptr, nullptr, out, Tn, Tn / 128, Dn / 128,
      512, 2, down_w, dwb, NWE8);

  // K4: expert GLU, clean (4096 blocks)
  kglu_bf<true><<<4096, 256, 0, stream>>>(
      xb, ids, gwb, upb, gb, up_b, H, Fn, CAPn, CAPn / 128, Fn / 128,
      4096, 0, nullptr, nullptr, 0, nullptr, nullptr, 0,
      0, nullptr, nullptr, nullptr);

  // K5: expert down, fat-N tile (512 blocks = 2/CU, one slot-round)
  kdown256<<<(CAPn / 128) * (Dn / 256) * En, 256, 0, stream>>>(
      H, dwb, down_b, ids, osc, out);
}